// Round 2
// baseline (2772.157 us; speedup 1.0000x reference)
//
#include <hip/hip_runtime.h>
#include <hip/hip_bf16.h>
#include <math.h>

#define D_    1152
#define H_    16
#define HD    72
#define E_    8
#define MLPH  4608
#define B_    8
#define S_    256
#define N_TOK 2048

// ---------------------------------------------------------------------------
// mod = silu(c) @ adaln_w + adaln_b      (8 x 4608)
// grid (4608/256, 8), block 256
__global__ void adaln_kernel(const float* __restrict__ c, const float* __restrict__ w,
                             const float* __restrict__ bias, float* __restrict__ mod) {
    __shared__ float sc[D_];
    int b = blockIdx.y;
    int j = blockIdx.x * 256 + threadIdx.x;
    for (int d = threadIdx.x; d < D_; d += 256) {
        float v = c[b * D_ + d];
        sc[d] = v / (1.f + __expf(-v));
    }
    __syncthreads();
    float acc = bias[j];
    for (int d = 0; d < D_; ++d)
        acc += sc[d] * w[(size_t)d * (4 * D_) + j];
    mod[b * (4 * D_) + j] = acc;
}

// ---------------------------------------------------------------------------
// LayerNorm (biased var, eps=1e-6); optionally apply adaLN modulation.
__global__ void ln_kernel(const float* __restrict__ x, const float* __restrict__ mod,
                          float* __restrict__ out, int use_mod) {
    int n = blockIdx.x;
    int b = n / S_;
    const float* xr = x + (size_t)n * D_;
    float s = 0.f, s2 = 0.f;
    for (int d = threadIdx.x; d < D_; d += 256) {
        float v = xr[d];
        s += v; s2 += v * v;
    }
    for (int off = 32; off > 0; off >>= 1) {
        s  += __shfl_down(s,  off);
        s2 += __shfl_down(s2, off);
    }
    __shared__ float wsum[4], wsum2[4], stats[2];
    int wid = threadIdx.x >> 6, lane = threadIdx.x & 63;
    if (lane == 0) { wsum[wid] = s; wsum2[wid] = s2; }
    __syncthreads();
    if (threadIdx.x == 0) {
        float ts = 0.f, ts2 = 0.f;
        for (int i = 0; i < 4; ++i) { ts += wsum[i]; ts2 += wsum2[i]; }
        float m = ts / D_;
        float var = ts2 / D_ - m * m;
        stats[0] = m; stats[1] = rsqrtf(var + 1e-6f);
    }
    __syncthreads();
    float m = stats[0], inv = stats[1];
    for (int d = threadIdx.x; d < D_; d += 256) {
        float v = (xr[d] - m) * inv;
        if (use_mod)
            v = v * (1.f + mod[b * (4 * D_) + D_ + d]) + mod[b * (4 * D_) + d];
        out[(size_t)n * D_ + d] = v;
    }
}

// ---------------------------------------------------------------------------
// fp32 GEMM, BM x 128 block tile (BM = 16*MI), 256 threads, MI x 8 micro-tile,
// BK=16, double-buffered LDS with ONE barrier per K-tile, register prefetch,
// XCD-chunked block swizzle (blocks sharing a B-panel co-resident per XCD L2).
//   MODE 0: dense  C = A @ B + bias
//   MODE 1: moe1   h1[outmap[p]] = gelu(A[rowmap[p]] @ B[e] + bias[e])
//   MODE 2: moe2   eo[outmap[p]] = A[rowmap[p]] @ B[e] + bias[e]
// Grid: x = (N/128)*(M/BM) flattened (must be divisible by 8), z = experts.
template<int MODE, int MI>
__global__ __launch_bounds__(256) void gemm_dbuf(
    const float* __restrict__ A, const float* __restrict__ Bg,
    const float* __restrict__ biasg, float* __restrict__ C,
    int M, int N, int K,
    const int* __restrict__ counts,
    const int* __restrict__ rowmap,
    const int* __restrict__ outmap) {
    constexpr int BM = 16 * MI;
    int e = (MODE == 0) ? 0 : (int)blockIdx.z;
    int cnt = (MODE == 0) ? M : counts[e];
    int NT = N >> 7;
    int MT = M / BM;
    int nb = NT * MT;
    int bx = blockIdx.x;
    // XCD chunking: consecutive w within one XCD -> m-blocks of one n-panel share L2
    int w = (bx & 7) * (nb >> 3) + (bx >> 3);
    int n0 = (w / MT) << 7;
    int m0 = (w % MT) * BM;
    if (m0 >= cnt) return;

    const float* B = Bg + (size_t)e * K * N;
    const float* bias = biasg + (size_t)e * N;

    __shared__ float As[2][16][BM];
    __shared__ float Bs[2][16][128];

    int tid = threadIdx.x;
    int tx = tid & 15, ty = tid >> 4;

    // A staging: BM*4 threads, one float4 each (row r0, k-quad kq4)
    int r0 = tid >> 2, kq4 = (tid & 3) * 4;
    bool aload = (tid < BM * 4);
    const float* ap = A;
    if (aload) {
        int p = m0 + r0;
        int g = (MODE == 0) ? p : rowmap[e * N_TOK + (p < cnt ? p : 0)];
        ap = A + (size_t)g * K + kq4;
    }
    // B staging: rows rb, rb+8; 128 cols per 32 lanes
    int rb = tid >> 5;
    int bc = (tid & 31) * 4;
    const float* bp = B + (size_t)rb * N + n0 + bc;

    float4 av = aload ? *(const float4*)(ap) : make_float4(0, 0, 0, 0);
    float4 bv0 = *(const float4*)(bp);
    float4 bv1 = *(const float4*)(bp + 8 * (size_t)N);

    // write tile 0 into buffer 0
    if (aload) {
        As[0][kq4 + 0][r0] = av.x; As[0][kq4 + 1][r0] = av.y;
        As[0][kq4 + 2][r0] = av.z; As[0][kq4 + 3][r0] = av.w;
    }
    *(float4*)&Bs[0][rb][bc] = bv0;
    *(float4*)&Bs[0][rb + 8][bc] = bv1;
    __syncthreads();

    float acc[MI][8] = {};
    int nt = K >> 4;
    for (int t = 0; t < nt; ++t) {
        int cur = t & 1, nxt = cur ^ 1;
        if (t + 1 < nt) {   // prefetch next tile into registers (hides under compute)
            int k0 = (t + 1) << 4;
            if (aload) av = *(const float4*)(ap + k0);
            bv0 = *(const float4*)(bp + (size_t)k0 * N);
            bv1 = *(const float4*)(bp + (size_t)(k0 + 8) * N);
        }
#pragma unroll
        for (int k = 0; k < 16; ++k) {
            float a[MI], b[8];
            if constexpr (MI == 4) {
                *(float4*)&a[0] = *(const float4*)&As[cur][k][ty * 4];
            } else {
                *(float2*)&a[0] = *(const float2*)&As[cur][k][ty * 2];
            }
            *(float4*)&b[0] = *(const float4*)&Bs[cur][k][tx * 4];
            *(float4*)&b[4] = *(const float4*)&Bs[cur][k][64 + tx * 4];
#pragma unroll
            for (int i = 0; i < MI; ++i)
#pragma unroll
                for (int j = 0; j < 8; ++j)
                    acc[i][j] += a[i] * b[j];
        }
        if (t + 1 < nt) {
            // safe: everyone passed barrier(t-1), so nobody still reads buf nxt
            if (aload) {
                As[nxt][kq4 + 0][r0] = av.x; As[nxt][kq4 + 1][r0] = av.y;
                As[nxt][kq4 + 2][r0] = av.z; As[nxt][kq4 + 3][r0] = av.w;
            }
            *(float4*)&Bs[nxt][rb][bc] = bv0;
            *(float4*)&Bs[nxt][rb + 8][bc] = bv1;
            __syncthreads();
        }
    }

#pragma unroll
    for (int i = 0; i < MI; ++i) {
        int pr = m0 + ty * MI + i;
        if (pr >= cnt) continue;
        size_t orow = (MODE == 0) ? (size_t)pr : (size_t)outmap[e * N_TOK + pr];
#pragma unroll
        for (int jn = 0; jn < 2; ++jn) {
            int col0 = n0 + jn * 64 + tx * 4;
            float4 o;
            float* op = &o.x;
#pragma unroll
            for (int j = 0; j < 4; ++j) {
                float v = acc[i][jn * 4 + j] + bias[col0 + j];
                if (MODE == 1) {
                    float u = 0.7978845608028654f * (v + 0.044715f * v * v * v);
                    v = 0.5f * v * (1.f + tanhf(u));
                }
                op[j] = v;
            }
            *(float4*)&C[orow * (size_t)N + col0] = o;
        }
    }
}

// ---------------------------------------------------------------------------
// Attention: one block per (q-tile of 16, head, batch). S=256 keys in 4x64 chunks.
__global__ __launch_bounds__(256) void attn_kernel(const float* __restrict__ qkv,
                                                   float* __restrict__ o) {
    int qt = blockIdx.x;  // 0..15
    int hh = blockIdx.y;  // 0..15
    int b  = blockIdx.z;  // 0..7
    __shared__ float qs[16][HD];
    __shared__ float kv[64][73];
    __shared__ float sc[16][256];
    __shared__ float rows[16];
    int tid = threadIdx.x;

    for (int i = tid; i < 16 * HD; i += 256) {
        int qi = i / HD, dd = i % HD;
        int n = b * S_ + qt * 16 + qi;
        qs[qi][dd] = qkv[(size_t)n * 3456 + hh * HD + dd];
    }
    int jj = tid & 63;
    int qg = tid >> 6;  // 0..3
    for (int c = 0; c < 4; ++c) {
        for (int i = tid; i < 64 * HD; i += 256) {
            int j = i / HD, dd = i % HD;
            int n = b * S_ + c * 64 + j;
            kv[j][dd] = qkv[(size_t)n * 3456 + D_ + hh * HD + dd];
        }
        __syncthreads();
#pragma unroll
        for (int qq = 0; qq < 4; ++qq) {
            int qi = qg * 4 + qq;
            float acc = 0.f;
            for (int dd = 0; dd < HD; ++dd) acc += qs[qi][dd] * kv[jj][dd];
            sc[qi][c * 64 + jj] = acc * 0.11785113019775793f;  // 72^-0.5
        }
        __syncthreads();
    }
    if (tid < 16) {
        float m = -1e30f;
        for (int j = 0; j < 256; ++j) m = fmaxf(m, sc[tid][j]);
        float s = 0.f;
        for (int j = 0; j < 256; ++j) {
            float e = __expf(sc[tid][j] - m);
            sc[tid][j] = e; s += e;
        }
        rows[tid] = s;
    }
    __syncthreads();
    float acc[5] = {0.f, 0.f, 0.f, 0.f, 0.f};
    for (int c = 0; c < 4; ++c) {
        for (int i = tid; i < 64 * HD; i += 256) {
            int j = i / HD, dd = i % HD;
            int n = b * S_ + c * 64 + j;
            kv[j][dd] = qkv[(size_t)n * 3456 + 2 * D_ + hh * HD + dd];
        }
        __syncthreads();
#pragma unroll
        for (int oi = 0; oi < 5; ++oi) {
            int oidx = oi * 256 + tid;
            if (oidx < 16 * HD) {
                int qi = oidx / HD, dd = oidx % HD;
                float a = acc[oi];
                for (int j = 0; j < 64; ++j) a += sc[qi][c * 64 + j] * kv[j][dd];
                acc[oi] = a;
            }
        }
        __syncthreads();
    }
    for (int oi = 0; oi < 5; ++oi) {
        int oidx = oi * 256 + tid;
        if (oidx < 16 * HD) {
            int qi = oidx / HD, dd = oidx % HD;
            int n = b * S_ + qt * 16 + qi;
            o[(size_t)n * D_ + hh * HD + dd] = acc[oi] / rows[qi];
        }
    }
}

// ---------------------------------------------------------------------------
// xa = x + gate_msa * o2
__global__ void residual1(const float* __restrict__ x, const float* __restrict__ o2,
                          const float* __restrict__ mod, float* __restrict__ xa) {
    int i = blockIdx.x * 256 + threadIdx.x;
    int n = i / D_, d = i % D_;
    int b = n / S_;
    xa[i] = x[i] + mod[b * (4 * D_) + 2 * D_ + d] * o2[i];
}

// ---------------------------------------------------------------------------
// Router: logits = nx @ gate_w + gate_b; top-2 + softmax; build expert lists.
__global__ void router_kernel(const float* __restrict__ nx, const float* __restrict__ gw,
                              const float* __restrict__ gb, int* __restrict__ counts,
                              int* __restrict__ etok, int* __restrict__ eslot,
                              int* __restrict__ tslot, float* __restrict__ tscore) {
    int n = blockIdx.x;
    int lane = threadIdx.x;
    float acc[E_] = {};
    for (int d = lane; d < D_; d += 64) {
        float v = nx[(size_t)n * D_ + d];
#pragma unroll
        for (int e = 0; e < E_; ++e) acc[e] += v * gw[d * E_ + e];
    }
#pragma unroll
    for (int e = 0; e < E_; ++e)
        for (int off = 32; off > 0; off >>= 1) acc[e] += __shfl_down(acc[e], off);
    if (lane == 0) {
        float lg[E_];
#pragma unroll
        for (int e = 0; e < E_; ++e) lg[e] = acc[e] + gb[e];
        int i0 = 0;
        for (int e = 1; e < E_; ++e) if (lg[e] > lg[i0]) i0 = e;
        int i1 = -1;
        for (int e = 0; e < E_; ++e) {
            if (e == i0) continue;
            if (i1 < 0 || lg[e] > lg[i1]) i1 = e;
        }
        float e1 = __expf(lg[i1] - lg[i0]);
        float p0 = 1.f / (1.f + e1), p1 = e1 / (1.f + e1);
        int p, slot;
        p = atomicAdd(&counts[i0], 1);
        slot = atomicAdd(&counts[8], 1);
        etok[i0 * N_TOK + p] = n; eslot[i0 * N_TOK + p] = slot;
        tslot[n * 2 + 0] = slot; tscore[n * 2 + 0] = p0;
        p = atomicAdd(&counts[i1], 1);
        slot = atomicAdd(&counts[8], 1);
        etok[i1 * N_TOK + p] = n; eslot[i1 * N_TOK + p] = slot;
        tslot[n * 2 + 1] = slot; tscore[n * 2 + 1] = p1;
    }
}

// ---------------------------------------------------------------------------
// out = xa + gate_mlp * (s0*eo[slot0] + s1*eo[slot1])
__global__ void combine_kernel(const float* __restrict__ xa, const float* __restrict__ eo,
                               const float* __restrict__ mod, const int* __restrict__ tslot,
                               const float* __restrict__ tscore, float* __restrict__ out) {
    int i = blockIdx.x * 256 + threadIdx.x;
    int n = i / D_, d = i % D_, b = n / S_;
    int s0 = tslot[n * 2 + 0], s1 = tslot[n * 2 + 1];
    float moe = tscore[n * 2 + 0] * eo[(size_t)s0 * D_ + d] +
                tscore[n * 2 + 1] * eo[(size_t)s1 * D_ + d];
    out[i] = xa[i] + mod[b * (4 * D_) + 3 * D_ + d] * moe;
}

__global__ void zero_counts(int* counts) {
    if (threadIdx.x < 16) counts[threadIdx.x] = 0;
}

// ---------------------------------------------------------------------------
extern "C" void kernel_launch(void* const* d_in, const int* in_sizes, int n_in,
                              void* d_out, int out_size, void* d_ws, size_t ws_size,
                              hipStream_t stream) {
    (void)in_sizes; (void)n_in; (void)out_size; (void)ws_size;
    const float* x       = (const float*)d_in[0];
    const float* c       = (const float*)d_in[1];
    const float* qkv_w   = (const float*)d_in[2];
    const float* qkv_b   = (const float*)d_in[3];
    const float* proj_w  = (const float*)d_in[4];
    const float* proj_b  = (const float*)d_in[5];
    const float* adaln_w = (const float*)d_in[6];
    const float* adaln_b = (const float*)d_in[7];
    const float* gate_w  = (const float*)d_in[8];
    const float* gate_b  = (const float*)d_in[9];
    const float* w1      = (const float*)d_in[10];
    const float* b1      = (const float*)d_in[11];
    const float* w2      = (const float*)d_in[12];
    const float* b2      = (const float*)d_in[13];

    float* ws = (float*)d_ws;
    float* mod  = ws;                         //      36864
    float* xa   = ws + 36864;                 //  2,359,296
    float* buf1 = ws + 2396160;               //  2,359,296  (h, later nx)
    float* qkvb = ws + 4755456;               //  7,077,888
    float* atto = ws + 11833344;              //  2,359,296
    float* o2   = ws + 14192640;              //  2,359,296
    float* h1   = ws + 4755456;               // 18,874,368 (after qkv/atto/o2 dead)
    float* eo   = ws + 23629824;              //  4,718,592 -> ends 28,348,416
    int*   counts = (int*)(ws + 28348416);    // 16
    int*   etok   = counts + 16;              // 16384
    int*   eslot  = etok + 16384;             // 16384
    int*   tslot  = eslot + 16384;            // 4096
    float* tscore = (float*)(tslot + 4096);   // 4096

    zero_counts<<<1, 64, 0, stream>>>(counts);
    adaln_kernel<<<dim3(18, 8), 256, 0, stream>>>(c, adaln_w, adaln_b, mod);
    ln_kernel<<<N_TOK, 256, 0, stream>>>(x, mod, buf1, 1);
    // qkv: M=2048 (BM64 -> 32 mt), N=3456 (27 nt) -> 864 blocks
    gemm_dbuf<0, 4><<<dim3(864), 256, 0, stream>>>(
        buf1, qkv_w, qkv_b, qkvb, N_TOK, 3456, D_, nullptr, nullptr, nullptr);
    attn_kernel<<<dim3(16, H_, B_), 256, 0, stream>>>(qkvb, atto);
    // proj: BM32 -> 64 mt, 9 nt -> 576 blocks
    gemm_dbuf<0, 2><<<dim3(576), 256, 0, stream>>>(
        atto, proj_w, proj_b, o2, N_TOK, D_, D_, nullptr, nullptr, nullptr);
    residual1<<<(N_TOK * D_) / 256, 256, 0, stream>>>(x, o2, mod, xa);
    ln_kernel<<<N_TOK, 256, 0, stream>>>(xa, nullptr, buf1, 0);
    router_kernel<<<N_TOK, 64, 0, stream>>>(buf1, gate_w, gate_b, counts, etok, eslot,
                                            tslot, tscore);
    // moe1: 36 nt * 32 mt = 1152 blocks/expert
    gemm_dbuf<1, 4><<<dim3(1152, 1, E_), 256, 0, stream>>>(
        buf1, w1, b1, h1, N_TOK, MLPH, D_, counts, etok, eslot);
    // moe2: 9 nt * 32 mt = 288 blocks/expert
    gemm_dbuf<2, 4><<<dim3(288, 1, E_), 256, 0, stream>>>(
        h1, w2, b2, eo, N_TOK, D_, MLPH, counts, eslot, eslot);
    combine_kernel<<<(N_TOK * D_) / 256, 256, 0, stream>>>(xa, eo, mod, tslot, tscore,
                                                           (float*)d_out);
}

// Round 3
// 1814.168 us; speedup vs baseline: 1.5281x; 1.5281x over previous
//
#include <hip/hip_runtime.h>
#include <math.h>

#define D_    1152
#define H_    16
#define HD    72
#define E_    8
#define MLPH  4608
#define B_    8
#define S_    256
#define N_TOK 2048

typedef __attribute__((ext_vector_type(8))) short bf16x8;
typedef __attribute__((ext_vector_type(4))) float f32x4;

__device__ __forceinline__ ushort bf_rne(float x) {
    uint u = __float_as_uint(x);
    return (ushort)((u + 0x7FFFu + ((u >> 16) & 1u)) >> 16);
}
__device__ __forceinline__ float bf_f(ushort h) {
    return __uint_as_float(((uint)h) << 16);
}

// ---------------------------------------------------------------------------
// Transpose + split: W[K][N] fp32  ->  hi/lo bf16 planes [N][K]
// grid (N/32, K/32, E), block 256
__global__ __launch_bounds__(256) void wsplit(const float* __restrict__ src,
                                              ushort* __restrict__ hi,
                                              ushort* __restrict__ lo,
                                              int K, int N) {
    size_t off = (size_t)blockIdx.z * K * N;
    src += off; hi += off; lo += off;
    __shared__ float t[32][33];
    int k0 = blockIdx.y * 32, n0 = blockIdx.x * 32;
    int r = threadIdx.x >> 3, cq = (threadIdx.x & 7) * 4;
    float4 v = *(const float4*)&src[(size_t)(k0 + r) * N + n0 + cq];
    t[r][cq + 0] = v.x; t[r][cq + 1] = v.y; t[r][cq + 2] = v.z; t[r][cq + 3] = v.w;
    __syncthreads();
    int n = threadIdx.x >> 3, kq = (threadIdx.x & 7) * 4;
    ushort4 hv, lv;
    {
        float f0 = t[kq + 0][n], f1 = t[kq + 1][n], f2 = t[kq + 2][n], f3 = t[kq + 3][n];
        hv.x = bf_rne(f0); lv.x = bf_rne(f0 - bf_f(hv.x));
        hv.y = bf_rne(f1); lv.y = bf_rne(f1 - bf_f(hv.y));
        hv.z = bf_rne(f2); lv.z = bf_rne(f2 - bf_f(hv.z));
        hv.w = bf_rne(f3); lv.w = bf_rne(f3 - bf_f(hv.w));
    }
    size_t o = (size_t)(n0 + n) * K + k0 + kq;
    *(ushort4*)&hi[o] = hv;
    *(ushort4*)&lo[o] = lv;
}

// ---------------------------------------------------------------------------
// MFMA GEMM, bf16x3 split (fp32-accurate): C = A @ W + bias.
// Tile 128x128, BK=32, 256 threads = 4 waves in 2x2, wave tile 64x64
// (4x4 fragments of 16x16x32). W given pre-transposed+split: hi/lo bf16 [N][K].
//   MODE 0: dense            MODE 1: moe up (gelu, gather/scatter)
//   MODE 2: moe down (gather/scatter)
template<int MODE>
__global__ __launch_bounds__(256) void mfma_gemm(
    const float* __restrict__ A, const ushort* __restrict__ WHg,
    const ushort* __restrict__ WLg, const float* __restrict__ biasg,
    float* __restrict__ C, int M, int N, int K,
    const int* __restrict__ counts, const int* __restrict__ rowmap,
    const int* __restrict__ outmap) {
    int e = (MODE == 0) ? 0 : (int)blockIdx.z;
    int cnt = (MODE == 0) ? M : counts[e];
    int m0 = blockIdx.y * 128;
    if (m0 >= cnt) return;
    int n0 = blockIdx.x * 128;
    const ushort* WH = WHg + (size_t)e * K * N;
    const ushort* WL = WLg + (size_t)e * K * N;
    const float* bias = biasg + (size_t)e * N;

    // fragment-ordered LDS: [frag][lane*8 bf16], frag stride 528 ushorts (1056B)
    __shared__ __align__(16) ushort Ah[8][528], Al[8][528], Bh[8][528], Bl[8][528];

    int tid = threadIdx.x;
    int lane = tid & 63, wid = tid >> 6;
    int wr = wid >> 1, wc = wid & 1;

    // A staging: thread -> row ar (0..127), k-half ah
    int ar = tid >> 1, ah = tid & 1;
    const float* arow;
    {
        int p = m0 + ar;
        int g = (MODE == 0) ? p : rowmap[e * N_TOK + (p < cnt ? p : 0)];
        arow = A + (size_t)g * K;
    }
    int afrag = ar >> 4;
    int alm = ar & 15;

    // B staging: thread -> frag bnf (0..7), 2 lane-slots
    int bnf = tid >> 5, bsub = tid & 31;

    f32x4 acc[4][4];
#pragma unroll
    for (int i = 0; i < 4; ++i)
#pragma unroll
        for (int j = 0; j < 4; ++j) acc[i][j] = (f32x4){0.f, 0.f, 0.f, 0.f};

    for (int k0 = 0; k0 < K; k0 += 32) {
        if (k0) __syncthreads();   // previous tile's readers done
        // ---- stage A: 16 fp32 -> hi/lo bf16 fragments
        float f[16];
        {
            const float* s = arow + k0 + ah * 16;
            *(float4*)&f[0] = *(const float4*)(s);
            *(float4*)&f[4] = *(const float4*)(s + 4);
            *(float4*)&f[8] = *(const float4*)(s + 8);
            *(float4*)&f[12] = *(const float4*)(s + 12);
        }
#pragma unroll
        for (int grp = 0; grp < 2; ++grp) {
            uint hv[4], lv[4];
#pragma unroll
            for (int jj = 0; jj < 4; ++jj) {
                float v0 = f[grp * 8 + jj * 2], v1 = f[grp * 8 + jj * 2 + 1];
                ushort h0 = bf_rne(v0), h1 = bf_rne(v1);
                ushort l0 = bf_rne(v0 - bf_f(h0)), l1 = bf_rne(v1 - bf_f(h1));
                hv[jj] = (uint)h0 | ((uint)h1 << 16);
                lv[jj] = (uint)l0 | ((uint)l1 << 16);
            }
            int g = ah * 2 + grp;
            int l = g * 16 + alm;
            *(uint4*)&Ah[afrag][l * 8] = make_uint4(hv[0], hv[1], hv[2], hv[3]);
            *(uint4*)&Al[afrag][l * 8] = make_uint4(lv[0], lv[1], lv[2], lv[3]);
        }
        // ---- stage B: pure 16B copies from pre-split planes
#pragma unroll
        for (int s = 0; s < 2; ++s) {
            int l = bsub + s * 32;
            size_t ga = (size_t)(n0 + bnf * 16 + (l & 15)) * K + k0 + 8 * (l >> 4);
            *(uint4*)&Bh[bnf][l * 8] = *(const uint4*)&WH[ga];
            *(uint4*)&Bl[bnf][l * 8] = *(const uint4*)&WL[ga];
        }
        __syncthreads();
        // ---- compute: cache B frags, stream A frags, 3 MFMA per pair
        bf16x8 bhv[4], blv[4];
#pragma unroll
        for (int nf = 0; nf < 4; ++nf) {
            int fb = wc * 4 + nf;
            bhv[nf] = *(const bf16x8*)&Bh[fb][lane * 8];
            blv[nf] = *(const bf16x8*)&Bl[fb][lane * 8];
        }
#pragma unroll
        for (int mf = 0; mf < 4; ++mf) {
            int fa = wr * 4 + mf;
            bf16x8 a_h = *(const bf16x8*)&Ah[fa][lane * 8];
            bf16x8 a_l = *(const bf16x8*)&Al[fa][lane * 8];
#pragma unroll
            for (int nf = 0; nf < 4; ++nf) {
                acc[mf][nf] = __builtin_amdgcn_mfma_f32_16x16x32_bf16(a_h, bhv[nf], acc[mf][nf], 0, 0, 0);
                acc[mf][nf] = __builtin_amdgcn_mfma_f32_16x16x32_bf16(a_h, blv[nf], acc[mf][nf], 0, 0, 0);
                acc[mf][nf] = __builtin_amdgcn_mfma_f32_16x16x32_bf16(a_l, bhv[nf], acc[mf][nf], 0, 0, 0);
            }
        }
    }

    // ---- epilogue: C/D layout col=lane&15, row=(lane>>4)*4+reg (m89-verified)
    int lr = lane >> 4, lc = lane & 15;
    float bv[4];
#pragma unroll
    for (int nf = 0; nf < 4; ++nf) bv[nf] = bias[n0 + wc * 64 + nf * 16 + lc];
#pragma unroll
    for (int mf = 0; mf < 4; ++mf) {
#pragma unroll
        for (int rr = 0; rr < 4; ++rr) {
            int pr = m0 + wr * 64 + mf * 16 + lr * 4 + rr;
            if (MODE != 0 && pr >= cnt) continue;
            size_t orow = (MODE == 0) ? (size_t)pr : (size_t)outmap[e * N_TOK + pr];
            float* crow = C + orow * (size_t)N + n0 + wc * 64 + lc;
#pragma unroll
            for (int nf = 0; nf < 4; ++nf) {
                float v = acc[mf][nf][rr] + bv[nf];
                if (MODE == 1) {
                    float u = 0.7978845608028654f * (v + 0.044715f * v * v * v);
                    v = 0.5f * v * (1.f + tanhf(u));
                }
                crow[nf * 16] = v;
            }
        }
    }
}

// ---------------------------------------------------------------------------
// mod = silu(c) @ adaln_w + adaln_b      (8 x 4608)
__global__ void adaln_kernel(const float* __restrict__ c, const float* __restrict__ w,
                             const float* __restrict__ bias, float* __restrict__ mod) {
    __shared__ float sc[D_];
    int b = blockIdx.y;
    int j = blockIdx.x * 256 + threadIdx.x;
    for (int d = threadIdx.x; d < D_; d += 256) {
        float v = c[b * D_ + d];
        sc[d] = v / (1.f + __expf(-v));
    }
    __syncthreads();
    float acc = bias[j];
    for (int d = 0; d < D_; ++d)
        acc += sc[d] * w[(size_t)d * (4 * D_) + j];
    mod[b * (4 * D_) + j] = acc;
}

// ---------------------------------------------------------------------------
// LayerNorm (biased var, eps=1e-6); optionally apply adaLN modulation.
__global__ void ln_kernel(const float* __restrict__ x, const float* __restrict__ mod,
                          float* __restrict__ out, int use_mod) {
    int n = blockIdx.x;
    int b = n / S_;
    const float* xr = x + (size_t)n * D_;
    float s = 0.f, s2 = 0.f;
    for (int d = threadIdx.x; d < D_; d += 256) {
        float v = xr[d];
        s += v; s2 += v * v;
    }
    for (int off = 32; off > 0; off >>= 1) {
        s  += __shfl_down(s,  off);
        s2 += __shfl_down(s2, off);
    }
    __shared__ float wsum[4], wsum2[4], stats[2];
    int wid = threadIdx.x >> 6, lane = threadIdx.x & 63;
    if (lane == 0) { wsum[wid] = s; wsum2[wid] = s2; }
    __syncthreads();
    if (threadIdx.x == 0) {
        float ts = 0.f, ts2 = 0.f;
        for (int i = 0; i < 4; ++i) { ts += wsum[i]; ts2 += wsum2[i]; }
        float m = ts / D_;
        float var = ts2 / D_ - m * m;
        stats[0] = m; stats[1] = rsqrtf(var + 1e-6f);
    }
    __syncthreads();
    float m = stats[0], inv = stats[1];
    for (int d = threadIdx.x; d < D_; d += 256) {
        float v = (xr[d] - m) * inv;
        if (use_mod)
            v = v * (1.f + mod[b * (4 * D_) + D_ + d]) + mod[b * (4 * D_) + d];
        out[(size_t)n * D_ + d] = v;
    }
}

// ---------------------------------------------------------------------------
// Attention: one block per (q-tile of 16, head, batch). S=256 keys in 4x64 chunks.
__global__ __launch_bounds__(256) void attn_kernel(const float* __restrict__ qkv,
                                                   float* __restrict__ o) {
    int qt = blockIdx.x;  // 0..15
    int hh = blockIdx.y;  // 0..15
    int b  = blockIdx.z;  // 0..7
    __shared__ float qs[16][HD];
    __shared__ float kv[64][73];
    __shared__ float sc[16][256];
    __shared__ float rows[16];
    int tid = threadIdx.x;

    for (int i = tid; i < 16 * HD; i += 256) {
        int qi = i / HD, dd = i % HD;
        int n = b * S_ + qt * 16 + qi;
        qs[qi][dd] = qkv[(size_t)n * 3456 + hh * HD + dd];
    }
    int jj = tid & 63;
    int qg = tid >> 6;  // 0..3
    for (int c = 0; c < 4; ++c) {
        for (int i = tid; i < 64 * HD; i += 256) {
            int j = i / HD, dd = i % HD;
            int n = b * S_ + c * 64 + j;
            kv[j][dd] = qkv[(size_t)n * 3456 + D_ + hh * HD + dd];
        }
        __syncthreads();
#pragma unroll
        for (int qq = 0; qq < 4; ++qq) {
            int qi = qg * 4 + qq;
            float acc = 0.f;
            for (int dd = 0; dd < HD; ++dd) acc += qs[qi][dd] * kv[jj][dd];
            sc[qi][c * 64 + jj] = acc * 0.11785113019775793f;  // 72^-0.5
        }
        __syncthreads();
    }
    if (tid < 16) {
        float m = -1e30f;
        for (int j = 0; j < 256; ++j) m = fmaxf(m, sc[tid][j]);
        float s = 0.f;
        for (int j = 0; j < 256; ++j) {
            float e = __expf(sc[tid][j] - m);
            sc[tid][j] = e; s += e;
        }
        rows[tid] = s;
    }
    __syncthreads();
    float acc[5] = {0.f, 0.f, 0.f, 0.f, 0.f};
    for (int c = 0; c < 4; ++c) {
        for (int i = tid; i < 64 * HD; i += 256) {
            int j = i / HD, dd = i % HD;
            int n = b * S_ + c * 64 + j;
            kv[j][dd] = qkv[(size_t)n * 3456 + 2 * D_ + hh * HD + dd];
        }
        __syncthreads();
#pragma unroll
        for (int oi = 0; oi < 5; ++oi) {
            int oidx = oi * 256 + tid;
            if (oidx < 16 * HD) {
                int qi = oidx / HD, dd = oidx % HD;
                float a = acc[oi];
                for (int j = 0; j < 64; ++j) a += sc[qi][c * 64 + j] * kv[j][dd];
                acc[oi] = a;
            }
        }
        __syncthreads();
    }
    for (int oi = 0; oi < 5; ++oi) {
        int oidx = oi * 256 + tid;
        if (oidx < 16 * HD) {
            int qi = oidx / HD, dd = oidx % HD;
            int n = b * S_ + qt * 16 + qi;
            o[(size_t)n * D_ + hh * HD + dd] = acc[oi] / rows[qi];
        }
    }
}

// ---------------------------------------------------------------------------
// xa = x + gate_msa * o2
__global__ void residual1(const float* __restrict__ x, const float* __restrict__ o2,
                          const float* __restrict__ mod, float* __restrict__ xa) {
    int i = blockIdx.x * 256 + threadIdx.x;
    int n = i / D_, d = i % D_;
    int b = n / S_;
    xa[i] = x[i] + mod[b * (4 * D_) + 2 * D_ + d] * o2[i];
}

// ---------------------------------------------------------------------------
// Router: logits = nx @ gate_w + gate_b; top-2 + softmax; build expert lists.
__global__ void router_kernel(const float* __restrict__ nx, const float* __restrict__ gw,
                              const float* __restrict__ gb, int* __restrict__ counts,
                              int* __restrict__ etok, int* __restrict__ eslot,
                              int* __restrict__ tslot, float* __restrict__ tscore) {
    int n = blockIdx.x;
    int lane = threadIdx.x;
    float acc[E_] = {};
    for (int d = lane; d < D_; d += 64) {
        float v = nx[(size_t)n * D_ + d];
#pragma unroll
        for (int e = 0; e < E_; ++e) acc[e] += v * gw[d * E_ + e];
    }
#pragma unroll
    for (int e = 0; e < E_; ++e)
        for (int off = 32; off > 0; off >>= 1) acc[e] += __shfl_down(acc[e], off);
    if (lane == 0) {
        float lg[E_];
#pragma unroll
        for (int e = 0; e < E_; ++e) lg[e] = acc[e] + gb[e];
        int i0 = 0;
        for (int e = 1; e < E_; ++e) if (lg[e] > lg[i0]) i0 = e;
        int i1 = -1;
        for (int e = 0; e < E_; ++e) {
            if (e == i0) continue;
            if (i1 < 0 || lg[e] > lg[i1]) i1 = e;
        }
        float e1 = __expf(lg[i1] - lg[i0]);
        float p0 = 1.f / (1.f + e1), p1 = e1 / (1.f + e1);
        int p, slot;
        p = atomicAdd(&counts[i0], 1);
        slot = atomicAdd(&counts[8], 1);
        etok[i0 * N_TOK + p] = n; eslot[i0 * N_TOK + p] = slot;
        tslot[n * 2 + 0] = slot; tscore[n * 2 + 0] = p0;
        p = atomicAdd(&counts[i1], 1);
        slot = atomicAdd(&counts[8], 1);
        etok[i1 * N_TOK + p] = n; eslot[i1 * N_TOK + p] = slot;
        tslot[n * 2 + 1] = slot; tscore[n * 2 + 1] = p1;
    }
}

// ---------------------------------------------------------------------------
// out = xa + gate_mlp * (s0*eo[slot0] + s1*eo[slot1])
__global__ void combine_kernel(const float* __restrict__ xa, const float* __restrict__ eo,
                               const float* __restrict__ mod, const int* __restrict__ tslot,
                               const float* __restrict__ tscore, float* __restrict__ out) {
    int i = blockIdx.x * 256 + threadIdx.x;
    int n = i / D_, d = i % D_, b = n / S_;
    int s0 = tslot[n * 2 + 0], s1 = tslot[n * 2 + 1];
    float moe = tscore[n * 2 + 0] * eo[(size_t)s0 * D_ + d] +
                tscore[n * 2 + 1] * eo[(size_t)s1 * D_ + d];
    out[i] = xa[i] + mod[b * (4 * D_) + 3 * D_ + d] * moe;
}

__global__ void zero_counts(int* counts) {
    if (threadIdx.x < 16) counts[threadIdx.x] = 0;
}

// ---------------------------------------------------------------------------
extern "C" void kernel_launch(void* const* d_in, const int* in_sizes, int n_in,
                              void* d_out, int out_size, void* d_ws, size_t ws_size,
                              hipStream_t stream) {
    (void)in_sizes; (void)n_in; (void)out_size; (void)ws_size;
    const float* x       = (const float*)d_in[0];
    const float* c       = (const float*)d_in[1];
    const float* qkv_w   = (const float*)d_in[2];
    const float* qkv_b   = (const float*)d_in[3];
    const float* proj_w  = (const float*)d_in[4];
    const float* proj_b  = (const float*)d_in[5];
    const float* adaln_w = (const float*)d_in[6];
    const float* adaln_b = (const float*)d_in[7];
    const float* gate_w  = (const float*)d_in[8];
    const float* gate_b  = (const float*)d_in[9];
    const float* w1      = (const float*)d_in[10];
    const float* b1      = (const float*)d_in[11];
    const float* w2      = (const float*)d_in[12];
    const float* b2      = (const float*)d_in[13];

    float* ws = (float*)d_ws;
    float* mod  = ws;                         //      36864
    float* xa   = ws + 36864;                 //  2,359,296
    float* buf1 = ws + 2396160;               //  2,359,296  (h, later nx)
    float* qkvb = ws + 4755456;               //  7,077,888
    float* atto = ws + 11833344;              //  2,359,296
    float* o2   = ws + 14192640;              //  2,359,296
    float* h1   = ws + 4755456;               // 18,874,368 (after qkv/atto/o2 dead)
    float* eo   = ws + 23629824;              //  4,718,592 -> ends 28,348,416
    int*   counts = (int*)(ws + 28348416);    // 16
    int*   etok   = counts + 16;              // 16384
    int*   eslot  = etok + 16384;             // 16384
    int*   tslot  = eslot + 16384;            // 4096
    float* tscore = (float*)(tslot + 4096);   // 4096  -> ends 28,389,392 floats

    // bf16 hi/lo transposed weight planes (ushort), after the fp32 region
    ushort* wt = (ushort*)(ws + 28389392);
    ushort* qkvT_hi = wt;                       // 1152*3456 = 3,981,312
    ushort* qkvT_lo = qkvT_hi + 3981312;
    ushort* projT_hi = qkvT_lo + 3981312;       // 1152*1152 = 1,327,104
    ushort* projT_lo = projT_hi + 1327104;
    ushort* w1T_hi = projT_lo + 1327104;        // 8*1152*4608 = 42,467,328
    ushort* w1T_lo = w1T_hi + 42467328;
    ushort* w2T_hi = w1T_lo + 42467328;         // 8*4608*1152 = 42,467,328
    ushort* w2T_lo = w2T_hi + 42467328;

    zero_counts<<<1, 64, 0, stream>>>(counts);
    // weight transpose+split
    wsplit<<<dim3(3456 / 32, 1152 / 32, 1), 256, 0, stream>>>(qkv_w, qkvT_hi, qkvT_lo, 1152, 3456);
    wsplit<<<dim3(1152 / 32, 1152 / 32, 1), 256, 0, stream>>>(proj_w, projT_hi, projT_lo, 1152, 1152);
    wsplit<<<dim3(4608 / 32, 1152 / 32, E_), 256, 0, stream>>>(w1, w1T_hi, w1T_lo, 1152, 4608);
    wsplit<<<dim3(1152 / 32, 4608 / 32, E_), 256, 0, stream>>>(w2, w2T_hi, w2T_lo, 4608, 1152);

    adaln_kernel<<<dim3(18, 8), 256, 0, stream>>>(c, adaln_w, adaln_b, mod);
    ln_kernel<<<N_TOK, 256, 0, stream>>>(x, mod, buf1, 1);
    mfma_gemm<0><<<dim3(3456 / 128, N_TOK / 128), 256, 0, stream>>>(
        buf1, qkvT_hi, qkvT_lo, qkv_b, qkvb, N_TOK, 3456, D_, nullptr, nullptr, nullptr);
    attn_kernel<<<dim3(16, H_, B_), 256, 0, stream>>>(qkvb, atto);
    mfma_gemm<0><<<dim3(D_ / 128, N_TOK / 128), 256, 0, stream>>>(
        atto, projT_hi, projT_lo, proj_b, o2, N_TOK, D_, D_, nullptr, nullptr, nullptr);
    residual1<<<(N_TOK * D_) / 256, 256, 0, stream>>>(x, o2, mod, xa);
    ln_kernel<<<N_TOK, 256, 0, stream>>>(xa, nullptr, buf1, 0);
    router_kernel<<<N_TOK, 64, 0, stream>>>(buf1, gate_w, gate_b, counts, etok, eslot,
                                            tslot, tscore);
    mfma_gemm<1><<<dim3(MLPH / 128, N_TOK / 128, E_), 256, 0, stream>>>(
        buf1, w1T_hi, w1T_lo, b1, h1, N_TOK, MLPH, D_, counts, etok, eslot);
    mfma_gemm<2><<<dim3(D_ / 128, N_TOK / 128, E_), 256, 0, stream>>>(
        h1, w2T_hi, w2T_lo, b2, eo, N_TOK, D_, MLPH, counts, eslot, eslot);
    combine_kernel<<<(N_TOK * D_) / 256, 256, 0, stream>>>(xa, eo, mod, tslot, tscore,
                                                           (float*)d_out);
}

// Round 6
// 1498.203 us; speedup vs baseline: 1.8503x; 1.2109x over previous
//
#include <hip/hip_runtime.h>
#include <math.h>

#define D_    1152
#define H_    16
#define HD    72
#define E_    8
#define MLPH  4608
#define B_    8
#define S_    256
#define N_TOK 2048

typedef __attribute__((ext_vector_type(8))) short bf16x8;
typedef __attribute__((ext_vector_type(4))) float f32x4;

__device__ __forceinline__ ushort bf_rne(float x) {
    uint u = __float_as_uint(x);
    return (ushort)((u + 0x7FFFu + ((u >> 16) & 1u)) >> 16);
}
__device__ __forceinline__ float bf_f(ushort h) {
    return __uint_as_float(((uint)h) << 16);
}

// ---------------------------------------------------------------------------
// Transpose + split: W[K][N] fp32  ->  hi/lo bf16 planes [N][K]
// grid (N/32, K/32, E), block 256
__global__ __launch_bounds__(256) void wsplit(const float* __restrict__ src,
                                              ushort* __restrict__ hi,
                                              ushort* __restrict__ lo,
                                              int K, int N) {
    size_t off = (size_t)blockIdx.z * K * N;
    src += off; hi += off; lo += off;
    __shared__ float t[32][33];
    int k0 = blockIdx.y * 32, n0 = blockIdx.x * 32;
    int r = threadIdx.x >> 3, cq = (threadIdx.x & 7) * 4;
    float4 v = *(const float4*)&src[(size_t)(k0 + r) * N + n0 + cq];
    t[r][cq + 0] = v.x; t[r][cq + 1] = v.y; t[r][cq + 2] = v.z; t[r][cq + 3] = v.w;
    __syncthreads();
    int n = threadIdx.x >> 3, kq = (threadIdx.x & 7) * 4;
    ushort4 hv, lv;
    {
        float f0 = t[kq + 0][n], f1 = t[kq + 1][n], f2 = t[kq + 2][n], f3 = t[kq + 3][n];
        hv.x = bf_rne(f0); lv.x = bf_rne(f0 - bf_f(hv.x));
        hv.y = bf_rne(f1); lv.y = bf_rne(f1 - bf_f(hv.y));
        hv.z = bf_rne(f2); lv.z = bf_rne(f2 - bf_f(hv.z));
        hv.w = bf_rne(f3); lv.w = bf_rne(f3 - bf_f(hv.w));
    }
    size_t o = (size_t)(n0 + n) * K + k0 + kq;
    *(ushort4*)&hi[o] = hv;
    *(ushort4*)&lo[o] = lv;
}

// ---------------------------------------------------------------------------
// MFMA GEMM, bf16x3 split (fp32-accurate): C = A @ W + bias.
// Tile 128x128, BK=32, 256 threads = 4 waves in 2x2, wave tile 64x64
// (4x4 fragments of 16x16x32). W given pre-transposed+split: hi/lo bf16 [N][K].
//   MODE 0: dense            MODE 1: moe up (gelu, gather/scatter)
//   MODE 2: moe down (gather/scatter)
template<int MODE>
__global__ __launch_bounds__(256) void mfma_gemm(
    const float* __restrict__ A, const ushort* __restrict__ WHg,
    const ushort* __restrict__ WLg, const float* __restrict__ biasg,
    float* __restrict__ C, int M, int N, int K,
    const int* __restrict__ counts, const int* __restrict__ rowmap,
    const int* __restrict__ outmap) {
    int e = (MODE == 0) ? 0 : (int)blockIdx.z;
    int cnt = (MODE == 0) ? M : counts[e];
    int m0 = blockIdx.y * 128;
    if (m0 >= cnt) return;
    int n0 = blockIdx.x * 128;
    const ushort* WH = WHg + (size_t)e * K * N;
    const ushort* WL = WLg + (size_t)e * K * N;
    const float* bias = biasg + (size_t)e * N;

    // fragment-ordered LDS: [frag][lane*8 bf16], frag stride 528 ushorts (1056B)
    __shared__ __align__(16) ushort Ah[8][528], Al[8][528], Bh[8][528], Bl[8][528];

    int tid = threadIdx.x;
    int lane = tid & 63, wid = tid >> 6;
    int wr = wid >> 1, wc = wid & 1;

    // A staging: thread -> row ar (0..127), k-half ah
    int ar = tid >> 1, ah = tid & 1;
    const float* arow;
    {
        int p = m0 + ar;
        int g = (MODE == 0) ? p : rowmap[e * N_TOK + (p < cnt ? p : 0)];
        arow = A + (size_t)g * K;
    }
    int afrag = ar >> 4;
    int alm = ar & 15;

    // B staging: thread -> frag bnf (0..7), 2 lane-slots
    int bnf = tid >> 5, bsub = tid & 31;

    f32x4 acc[4][4];
#pragma unroll
    for (int i = 0; i < 4; ++i)
#pragma unroll
        for (int j = 0; j < 4; ++j) acc[i][j] = (f32x4){0.f, 0.f, 0.f, 0.f};

    for (int k0 = 0; k0 < K; k0 += 32) {
        if (k0) __syncthreads();   // previous tile's readers done
        // ---- stage A: 16 fp32 -> hi/lo bf16 fragments
        float f[16];
        {
            const float* s = arow + k0 + ah * 16;
            *(float4*)&f[0] = *(const float4*)(s);
            *(float4*)&f[4] = *(const float4*)(s + 4);
            *(float4*)&f[8] = *(const float4*)(s + 8);
            *(float4*)&f[12] = *(const float4*)(s + 12);
        }
#pragma unroll
        for (int grp = 0; grp < 2; ++grp) {
            uint hv[4], lv[4];
#pragma unroll
            for (int jj = 0; jj < 4; ++jj) {
                float v0 = f[grp * 8 + jj * 2], v1 = f[grp * 8 + jj * 2 + 1];
                ushort h0 = bf_rne(v0), h1 = bf_rne(v1);
                ushort l0 = bf_rne(v0 - bf_f(h0)), l1 = bf_rne(v1 - bf_f(h1));
                hv[jj] = (uint)h0 | ((uint)h1 << 16);
                lv[jj] = (uint)l0 | ((uint)l1 << 16);
            }
            int g = ah * 2 + grp;
            int l = g * 16 + alm;
            *(uint4*)&Ah[afrag][l * 8] = make_uint4(hv[0], hv[1], hv[2], hv[3]);
            *(uint4*)&Al[afrag][l * 8] = make_uint4(lv[0], lv[1], lv[2], lv[3]);
        }
        // ---- stage B: pure 16B copies from pre-split planes
#pragma unroll
        for (int s = 0; s < 2; ++s) {
            int l = bsub + s * 32;
            size_t ga = (size_t)(n0 + bnf * 16 + (l & 15)) * K + k0 + 8 * (l >> 4);
            *(uint4*)&Bh[bnf][l * 8] = *(const uint4*)&WH[ga];
            *(uint4*)&Bl[bnf][l * 8] = *(const uint4*)&WL[ga];
        }
        __syncthreads();
        // ---- compute: cache B frags, stream A frags, 3 MFMA per pair
        bf16x8 bhv[4], blv[4];
#pragma unroll
        for (int nf = 0; nf < 4; ++nf) {
            int fb = wc * 4 + nf;
            bhv[nf] = *(const bf16x8*)&Bh[fb][lane * 8];
            blv[nf] = *(const bf16x8*)&Bl[fb][lane * 8];
        }
#pragma unroll
        for (int mf = 0; mf < 4; ++mf) {
            int fa = wr * 4 + mf;
            bf16x8 a_h = *(const bf16x8*)&Ah[fa][lane * 8];
            bf16x8 a_l = *(const bf16x8*)&Al[fa][lane * 8];
#pragma unroll
            for (int nf = 0; nf < 4; ++nf) {
                acc[mf][nf] = __builtin_amdgcn_mfma_f32_16x16x32_bf16(a_h, bhv[nf], acc[mf][nf], 0, 0, 0);
                acc[mf][nf] = __builtin_amdgcn_mfma_f32_16x16x32_bf16(a_h, blv[nf], acc[mf][nf], 0, 0, 0);
                acc[mf][nf] = __builtin_amdgcn_mfma_f32_16x16x32_bf16(a_l, bhv[nf], acc[mf][nf], 0, 0, 0);
            }
        }
    }

    // ---- epilogue: C/D layout col=lane&15, row=(lane>>4)*4+reg (m89-verified)
    int lr = lane >> 4, lc = lane & 15;
    float bv[4];
#pragma unroll
    for (int nf = 0; nf < 4; ++nf) bv[nf] = bias[n0 + wc * 64 + nf * 16 + lc];
#pragma unroll
    for (int mf = 0; mf < 4; ++mf) {
#pragma unroll
        for (int rr = 0; rr < 4; ++rr) {
            int pr = m0 + wr * 64 + mf * 16 + lr * 4 + rr;
            if (MODE != 0 && pr >= cnt) continue;
            size_t orow = (MODE == 0) ? (size_t)pr : (size_t)outmap[e * N_TOK + pr];
            float* crow = C + orow * (size_t)N + n0 + wc * 64 + lc;
#pragma unroll
            for (int nf = 0; nf < 4; ++nf) {
                float v = acc[mf][nf][rr] + bv[nf];
                if (MODE == 1) {
                    float u = 0.7978845608028654f * (v + 0.044715f * v * v * v);
                    v = 0.5f * v * (1.f + tanhf(u));
                }
                crow[nf * 16] = v;
            }
        }
    }
}

// ---------------------------------------------------------------------------
// mod = silu(c) @ adaln_w + adaln_b      (8 x 4608)
__global__ void adaln_kernel(const float* __restrict__ c, const float* __restrict__ w,
                             const float* __restrict__ bias, float* __restrict__ mod) {
    __shared__ float sc[D_];
    int b = blockIdx.y;
    int j = blockIdx.x * 256 + threadIdx.x;
    for (int d = threadIdx.x; d < D_; d += 256) {
        float v = c[b * D_ + d];
        sc[d] = v / (1.f + __expf(-v));
    }
    __syncthreads();
    float acc = bias[j];
    for (int d = 0; d < D_; ++d)
        acc += sc[d] * w[(size_t)d * (4 * D_) + j];
    mod[b * (4 * D_) + j] = acc;
}

// ---------------------------------------------------------------------------
// LayerNorm (biased var, eps=1e-6); optionally apply adaLN modulation.
__global__ void ln_kernel(const float* __restrict__ x, const float* __restrict__ mod,
                          float* __restrict__ out, int use_mod) {
    int n = blockIdx.x;
    int b = n / S_;
    const float* xr = x + (size_t)n * D_;
    float s = 0.f, s2 = 0.f;
    for (int d = threadIdx.x; d < D_; d += 256) {
        float v = xr[d];
        s += v; s2 += v * v;
    }
    for (int off = 32; off > 0; off >>= 1) {
        s  += __shfl_down(s,  off);
        s2 += __shfl_down(s2, off);
    }
    __shared__ float wsum[4], wsum2[4], stats[2];
    int wid = threadIdx.x >> 6, lane = threadIdx.x & 63;
    if (lane == 0) { wsum[wid] = s; wsum2[wid] = s2; }
    __syncthreads();
    if (threadIdx.x == 0) {
        float ts = 0.f, ts2 = 0.f;
        for (int i = 0; i < 4; ++i) { ts += wsum[i]; ts2 += wsum2[i]; }
        float m = ts / D_;
        float var = ts2 / D_ - m * m;
        stats[0] = m; stats[1] = rsqrtf(var + 1e-6f);
    }
    __syncthreads();
    float m = stats[0], inv = stats[1];
    for (int d = threadIdx.x; d < D_; d += 256) {
        float v = (xr[d] - m) * inv;
        if (use_mod)
            v = v * (1.f + mod[b * (4 * D_) + D_ + d]) + mod[b * (4 * D_) + d];
        out[(size_t)n * D_ + d] = v;
    }
}

// ---------------------------------------------------------------------------
// Attention v2: block = (q-tile of 32, head, batch) -> grid (8,16,8), 256 thr.
// Row-major LDS tiles with odd-mod-32 pads (77) for conflict-free scalar reads;
// Pe stride 257 (==1 mod 32); wave-parallel softmax; PV micro-tile 2q x 4dd.
// All LDS arrays explicitly 16B-aligned (float4 LDS ops require it).
__global__ __launch_bounds__(256) void attn_kernel(const float* __restrict__ qkv,
                                                   float* __restrict__ o) {
    int qt = blockIdx.x;   // 0..7
    int hh = blockIdx.y;   // 0..15
    int b  = blockIdx.z;   // 0..7
    __shared__ __align__(16) float Pe[32][257];   // raw scores, then exp'd probs
    __shared__ __align__(16) float Qs[32][77];
    __shared__ __align__(16) float Ks[32][77];
    __shared__ __align__(16) float Vs[32][76];
    __shared__ __align__(16) float sm[8][32];
    __shared__ __align__(16) float rinv[32];
    int t = threadIdx.x;
    const float scale = 0.11785113019775793f;  // 72^-0.5

    // ---- stage Q tile (32 rows x 72), coalesced float4 reads, scalar LDS writes
    for (int i = t; i < 576; i += 256) {
        int r = i / 18, quad = i % 18;
        int n = b * S_ + qt * 32 + r;
        float4 v = *(const float4*)&qkv[(size_t)n * 3456 + hh * HD + quad * 4];
        Qs[r][quad * 4 + 0] = v.x; Qs[r][quad * 4 + 1] = v.y;
        Qs[r][quad * 4 + 2] = v.z; Qs[r][quad * 4 + 3] = v.w;
    }

    // ---- QK^T: 8 key-chunks of 32; thread = (q-row ty, k-quad tx)
    int tx = t & 7, ty = t >> 3;
    for (int c = 0; c < 8; ++c) {
        __syncthreads();   // Qs ready (c==0) / prev chunk's readers done
        for (int i = t; i < 576; i += 256) {
            int r = i / 18, quad = i % 18;
            int n = b * S_ + c * 32 + r;
            float4 v = *(const float4*)&qkv[(size_t)n * 3456 + D_ + hh * HD + quad * 4];
            Ks[r][quad * 4 + 0] = v.x; Ks[r][quad * 4 + 1] = v.y;
            Ks[r][quad * 4 + 2] = v.z; Ks[r][quad * 4 + 3] = v.w;
        }
        __syncthreads();
        float a0 = 0.f, a1 = 0.f, a2 = 0.f, a3 = 0.f;
        const float* q_r = &Qs[ty][0];
        const float* k0r = &Ks[tx * 4 + 0][0];
        const float* k1r = &Ks[tx * 4 + 1][0];
        const float* k2r = &Ks[tx * 4 + 2][0];
        const float* k3r = &Ks[tx * 4 + 3][0];
#pragma unroll 8
        for (int dd = 0; dd < HD; ++dd) {
            float qv = q_r[dd];
            a0 += qv * k0r[dd]; a1 += qv * k1r[dd];
            a2 += qv * k2r[dd]; a3 += qv * k3r[dd];
        }
        Pe[ty][c * 32 + tx * 4 + 0] = a0 * scale;
        Pe[ty][c * 32 + tx * 4 + 1] = a1 * scale;
        Pe[ty][c * 32 + tx * 4 + 2] = a2 * scale;
        Pe[ty][c * 32 + tx * 4 + 3] = a3 * scale;
    }
    __syncthreads();

    // ---- softmax: 32 rows x 8 segments, fully parallel
    int r = t & 31, oct = t >> 5;
    float m = -1e30f;
#pragma unroll 8
    for (int k = 0; k < 32; ++k) m = fmaxf(m, Pe[r][oct * 32 + k]);
    sm[oct][r] = m;
    __syncthreads();
    float mm = sm[0][r];
#pragma unroll
    for (int i = 1; i < 8; ++i) mm = fmaxf(mm, sm[i][r]);
    __syncthreads();   // all reads of sm(max) done before reuse for sums
    float s = 0.f;
#pragma unroll 8
    for (int k = 0; k < 32; ++k) {
        float e = __expf(Pe[r][oct * 32 + k] - mm);
        Pe[r][oct * 32 + k] = e;
        s += e;
    }
    sm[oct][r] = s;
    __syncthreads();
    if (oct == 0) {
        float ts = 0.f;
#pragma unroll
        for (int i = 0; i < 8; ++i) ts += sm[i][r];
        rinv[r] = 1.f / ts;
    }

    // ---- PV: main thread = (q-pair qg, dd-quad dq) covers dd 0..63;
    //      tail (wave 0) = (q tq, dd-quad 16/17) covers dd 64..71
    int dq = t & 15, qg = t >> 4;
    int tq = t & 31, tquad = 16 + (t >> 5);
    float4 acc0 = {0.f, 0.f, 0.f, 0.f}, acc1 = {0.f, 0.f, 0.f, 0.f};
    float4 acct = {0.f, 0.f, 0.f, 0.f};
    for (int c = 0; c < 8; ++c) {
        __syncthreads();   // exp writes (c==0) / prev chunk readers done
        for (int i = t; i < 576; i += 256) {
            int rr = i / 18, quad = i % 18;
            int n = b * S_ + c * 32 + rr;
            float4 v = *(const float4*)&qkv[(size_t)n * 3456 + 2 * D_ + hh * HD + quad * 4];
            *(float4*)&Vs[rr][quad * 4] = v;
        }
        __syncthreads();
#pragma unroll 4
        for (int j = 0; j < 32; ++j) {
            float4 v4 = *(const float4*)&Vs[j][dq * 4];
            float p0 = Pe[qg * 2 + 0][c * 32 + j];
            float p1 = Pe[qg * 2 + 1][c * 32 + j];
            acc0.x += p0 * v4.x; acc0.y += p0 * v4.y;
            acc0.z += p0 * v4.z; acc0.w += p0 * v4.w;
            acc1.x += p1 * v4.x; acc1.y += p1 * v4.y;
            acc1.z += p1 * v4.z; acc1.w += p1 * v4.w;
        }
        if (t < 64) {
#pragma unroll 4
            for (int j = 0; j < 32; ++j) {
                float4 v4 = *(const float4*)&Vs[j][tquad * 4];
                float p = Pe[tq][c * 32 + j];
                acct.x += p * v4.x; acct.y += p * v4.y;
                acct.z += p * v4.z; acct.w += p * v4.w;
            }
        }
    }

    // ---- write O
    {
        int n0 = b * S_ + qt * 32;
        float ri0 = rinv[qg * 2 + 0], ri1 = rinv[qg * 2 + 1];
        float4 o0, o1;
        o0.x = acc0.x * ri0; o0.y = acc0.y * ri0; o0.z = acc0.z * ri0; o0.w = acc0.w * ri0;
        o1.x = acc1.x * ri1; o1.y = acc1.y * ri1; o1.z = acc1.z * ri1; o1.w = acc1.w * ri1;
        *(float4*)&o[(size_t)(n0 + qg * 2 + 0) * D_ + hh * HD + dq * 4] = o0;
        *(float4*)&o[(size_t)(n0 + qg * 2 + 1) * D_ + hh * HD + dq * 4] = o1;
        if (t < 64) {
            float rit = rinv[tq];
            float4 ot;
            ot.x = acct.x * rit; ot.y = acct.y * rit; ot.z = acct.z * rit; ot.w = acct.w * rit;
            *(float4*)&o[(size_t)(n0 + tq) * D_ + hh * HD + tquad * 4] = ot;
        }
    }
}

// ---------------------------------------------------------------------------
// xa = x + gate_msa * o2
__global__ void residual1(const float* __restrict__ x, const float* __restrict__ o2,
                          const float* __restrict__ mod, float* __restrict__ xa) {
    int i = blockIdx.x * 256 + threadIdx.x;
    int n = i / D_, d = i % D_;
    int b = n / S_;
    xa[i] = x[i] + mod[b * (4 * D_) + 2 * D_ + d] * o2[i];
}

// ---------------------------------------------------------------------------
// Router: logits = nx @ gate_w + gate_b; top-2 + softmax; build expert lists.
__global__ void router_kernel(const float* __restrict__ nx, const float* __restrict__ gw,
                              const float* __restrict__ gb, int* __restrict__ counts,
                              int* __restrict__ etok, int* __restrict__ eslot,
                              int* __restrict__ tslot, float* __restrict__ tscore) {
    int n = blockIdx.x;
    int lane = threadIdx.x;
    float acc[E_] = {};
    for (int d = lane; d < D_; d += 64) {
        float v = nx[(size_t)n * D_ + d];
#pragma unroll
        for (int e = 0; e < E_; ++e) acc[e] += v * gw[d * E_ + e];
    }
#pragma unroll
    for (int e = 0; e < E_; ++e)
        for (int off = 32; off > 0; off >>= 1) acc[e] += __shfl_down(acc[e], off);
    if (lane == 0) {
        float lg[E_];
#pragma unroll
        for (int e = 0; e < E_; ++e) lg[e] = acc[e] + gb[e];
        int i0 = 0;
        for (int e = 1; e < E_; ++e) if (lg[e] > lg[i0]) i0 = e;
        int i1 = -1;
        for (int e = 0; e < E_; ++e) {
            if (e == i0) continue;
            if (i1 < 0 || lg[e] > lg[i1]) i1 = e;
        }
        float e1 = __expf(lg[i1] - lg[i0]);
        float p0 = 1.f / (1.f + e1), p1 = e1 / (1.f + e1);
        int p, slot;
        p = atomicAdd(&counts[i0], 1);
        slot = atomicAdd(&counts[8], 1);
        etok[i0 * N_TOK + p] = n; eslot[i0 * N_TOK + p] = slot;
        tslot[n * 2 + 0] = slot; tscore[n * 2 + 0] = p0;
        p = atomicAdd(&counts[i1], 1);
        slot = atomicAdd(&counts[8], 1);
        etok[i1 * N_TOK + p] = n; eslot[i1 * N_TOK + p] = slot;
        tslot[n * 2 + 1] = slot; tscore[n * 2 + 1] = p1;
    }
}

// ---------------------------------------------------------------------------
// out = xa + gate_mlp * (s0*eo[slot0] + s1*eo[slot1])
__global__ void combine_kernel(const float* __restrict__ xa, const float* __restrict__ eo,
                               const float* __restrict__ mod, const int* __restrict__ tslot,
                               const float* __restrict__ tscore, float* __restrict__ out) {
    int i = blockIdx.x * 256 + threadIdx.x;
    int n = i / D_, d = i % D_, b = n / S_;
    int s0 = tslot[n * 2 + 0], s1 = tslot[n * 2 + 1];
    float moe = tscore[n * 2 + 0] * eo[(size_t)s0 * D_ + d] +
                tscore[n * 2 + 1] * eo[(size_t)s1 * D_ + d];
    out[i] = xa[i] + mod[b * (4 * D_) + 3 * D_ + d] * moe;
}

__global__ void zero_counts(int* counts) {
    if (threadIdx.x < 16) counts[threadIdx.x] = 0;
}

// ---------------------------------------------------------------------------
extern "C" void kernel_launch(void* const* d_in, const int* in_sizes, int n_in,
                              void* d_out, int out_size, void* d_ws, size_t ws_size,
                              hipStream_t stream) {
    (void)in_sizes; (void)n_in; (void)out_size; (void)ws_size;
    const float* x       = (const float*)d_in[0];
    const float* c       = (const float*)d_in[1];
    const float* qkv_w   = (const float*)d_in[2];
    const float* qkv_b   = (const float*)d_in[3];
    const float* proj_w  = (const float*)d_in[4];
    const float* proj_b  = (const float*)d_in[5];
    const float* adaln_w = (const float*)d_in[6];
    const float* adaln_b = (const float*)d_in[7];
    const float* gate_w  = (const float*)d_in[8];
    const float* gate_b  = (const float*)d_in[9];
    const float* w1      = (const float*)d_in[10];
    const float* b1      = (const float*)d_in[11];
    const float* w2      = (const float*)d_in[12];
    const float* b2      = (const float*)d_in[13];

    float* ws = (float*)d_ws;
    float* mod  = ws;                         //      36864
    float* xa   = ws + 36864;                 //  2,359,296
    float* buf1 = ws + 2396160;               //  2,359,296  (h, later nx)
    float* qkvb = ws + 4755456;               //  7,077,888
    float* atto = ws + 11833344;              //  2,359,296
    float* o2   = ws + 14192640;              //  2,359,296
    float* h1   = ws + 4755456;               // 18,874,368 (after qkv/atto/o2 dead)
    float* eo   = ws + 23629824;              //  4,718,592 -> ends 28,348,416
    int*   counts = (int*)(ws + 28348416);    // 16
    int*   etok   = counts + 16;              // 16384
    int*   eslot  = etok + 16384;             // 16384
    int*   tslot  = eslot + 16384;            // 4096
    float* tscore = (float*)(tslot + 4096);   // 4096  -> ends 28,389,392 floats

    // bf16 hi/lo transposed weight planes (ushort), after the fp32 region
    ushort* wt = (ushort*)(ws + 28389392);
    ushort* qkvT_hi = wt;                       // 1152*3456 = 3,981,312
    ushort* qkvT_lo = qkvT_hi + 3981312;
    ushort* projT_hi = qkvT_lo + 3981312;       // 1152*1152 = 1,327,104
    ushort* projT_lo = projT_hi + 1327104;
    ushort* w1T_hi = projT_lo + 1327104;        // 8*1152*4608 = 42,467,328
    ushort* w1T_lo = w1T_hi + 42467328;
    ushort* w2T_hi = w1T_lo + 42467328;         // 8*4608*1152 = 42,467,328
    ushort* w2T_lo = w2T_hi + 42467328;

    zero_counts<<<1, 64, 0, stream>>>(counts);
    // weight transpose+split
    wsplit<<<dim3(3456 / 32, 1152 / 32, 1), 256, 0, stream>>>(qkv_w, qkvT_hi, qkvT_lo, 1152, 3456);
    wsplit<<<dim3(1152 / 32, 1152 / 32, 1), 256, 0, stream>>>(proj_w, projT_hi, projT_lo, 1152, 1152);
    wsplit<<<dim3(4608 / 32, 1152 / 32, E_), 256, 0, stream>>>(w1, w1T_hi, w1T_lo, 1152, 4608);
    wsplit<<<dim3(1152 / 32, 4608 / 32, E_), 256, 0, stream>>>(w2, w2T_hi, w2T_lo, 4608, 1152);

    adaln_kernel<<<dim3(18, 8), 256, 0, stream>>>(c, adaln_w, adaln_b, mod);
    ln_kernel<<<N_TOK, 256, 0, stream>>>(x, mod, buf1, 1);
    mfma_gemm<0><<<dim3(3456 / 128, N_TOK / 128), 256, 0, stream>>>(
        buf1, qkvT_hi, qkvT_lo, qkv_b, qkvb, N_TOK, 3456, D_, nullptr, nullptr, nullptr);
    attn_kernel<<<dim3(8, H_, B_), 256, 0, stream>>>(qkvb, atto);
    mfma_gemm<0><<<dim3(D_ / 128, N_TOK / 128), 256, 0, stream>>>(
        atto, projT_hi, projT_lo, proj_b, o2, N_TOK, D_, D_, nullptr, nullptr, nullptr);
    residual1<<<(N_TOK * D_) / 256, 256, 0, stream>>>(x, o2, mod, xa);
    ln_kernel<<<N_TOK, 256, 0, stream>>>(xa, nullptr, buf1, 0);
    router_kernel<<<N_TOK, 64, 0, stream>>>(buf1, gate_w, gate_b, counts, etok, eslot,
                                            tslot, tscore);
    mfma_gemm<1><<<dim3(MLPH / 128, N_TOK / 128, E_), 256, 0, stream>>>(
        buf1, w1T_hi, w1T_lo, b1, h1, N_TOK, MLPH, D_, counts, etok, eslot);
    mfma_gemm<2><<<dim3(D_ / 128, N_TOK / 128, E_), 256, 0, stream>>>(
        h1, w2T_hi, w2T_lo, b2, eo, N_TOK, D_, MLPH, counts, eslot, eslot);
    combine_kernel<<<(N_TOK * D_) / 256, 256, 0, stream>>>(xa, eo, mod, tslot, tscore,
                                                           (float*)d_out);
}

// Round 7
// 1371.539 us; speedup vs baseline: 2.0212x; 1.0924x over previous
//
#include <hip/hip_runtime.h>
#include <math.h>

#define D_    1152
#define H_    16
#define HD    72
#define E_    8
#define MLPH  4608
#define B_    8
#define S_    256
#define N_TOK 2048

typedef __attribute__((ext_vector_type(8))) short bf16x8;
typedef __attribute__((ext_vector_type(4))) float f32x4;

__device__ __forceinline__ ushort bf_rne(float x) {
    uint u = __float_as_uint(x);
    return (ushort)((u + 0x7FFFu + ((u >> 16) & 1u)) >> 16);
}
__device__ __forceinline__ float bf_f(ushort h) {
    return __uint_as_float(((uint)h) << 16);
}

// ---------------------------------------------------------------------------
// Transpose + split: W[K][N] fp32  ->  hi/lo bf16 planes [N][K]
// grid (N/32, K/32, E), block 256
__global__ __launch_bounds__(256) void wsplit(const float* __restrict__ src,
                                              ushort* __restrict__ hi,
                                              ushort* __restrict__ lo,
                                              int K, int N) {
    size_t off = (size_t)blockIdx.z * K * N;
    src += off; hi += off; lo += off;
    __shared__ float t[32][33];
    int k0 = blockIdx.y * 32, n0 = blockIdx.x * 32;
    int r = threadIdx.x >> 3, cq = (threadIdx.x & 7) * 4;
    float4 v = *(const float4*)&src[(size_t)(k0 + r) * N + n0 + cq];
    t[r][cq + 0] = v.x; t[r][cq + 1] = v.y; t[r][cq + 2] = v.z; t[r][cq + 3] = v.w;
    __syncthreads();
    int n = threadIdx.x >> 3, kq = (threadIdx.x & 7) * 4;
    ushort4 hv, lv;
    {
        float f0 = t[kq + 0][n], f1 = t[kq + 1][n], f2 = t[kq + 2][n], f3 = t[kq + 3][n];
        hv.x = bf_rne(f0); lv.x = bf_rne(f0 - bf_f(hv.x));
        hv.y = bf_rne(f1); lv.y = bf_rne(f1 - bf_f(hv.y));
        hv.z = bf_rne(f2); lv.z = bf_rne(f2 - bf_f(hv.z));
        hv.w = bf_rne(f3); lv.w = bf_rne(f3 - bf_f(hv.w));
    }
    size_t o = (size_t)(n0 + n) * K + k0 + kq;
    *(ushort4*)&hi[o] = hv;
    *(ushort4*)&lo[o] = lv;
}

// ---------------------------------------------------------------------------
// MFMA GEMM, bf16x3 split (fp32-accurate): C = A @ W + bias.
// Tile 128x128, BK=32, 256 threads = 4 waves in 2x2, wave tile 64x64.
// v2: 1D swizzled grid.x (bijective XCD chunking over the ACTIVE (n,m) grid,
//     n-fastest -> A-panel L2 reuse), split-K (KS) with partial outputs at
//     C + kh*pstride (bias only on kh==0), register prefetch of tile t+1
//     issued before compute of tile t.
//   MODE 0: dense   MODE 1: moe up (gelu; KS must be 1)   MODE 2: moe down
template<int MODE, int KS>
__global__ __launch_bounds__(256) void mfma_gemm(
    const float* __restrict__ A, const ushort* __restrict__ WHg,
    const ushort* __restrict__ WLg, const float* __restrict__ biasg,
    float* __restrict__ C, int M, int N, int Ktot,
    unsigned long long pstride,
    const int* __restrict__ counts, const int* __restrict__ rowmap,
    const int* __restrict__ outmap) {
    int zz = (int)blockIdx.z;
    int kh = (KS == 1) ? 0 : (zz % KS);
    int e  = (KS == 1) ? zz : (zz / KS);
    int cnt = (MODE == 0) ? M : counts[e];
    int NTt = N >> 7;
    int MTa = (MODE == 0) ? (M >> 7) : ((cnt + 127) >> 7);
    int nb = NTt * MTa;
    int bx = (int)blockIdx.x;
    if (bx >= nb) return;
    // bijective XCD-chunked swizzle (id%8 -> XCD phase; grid.x % 8 == 0)
    int q = nb >> 3, r = nb & 7;
    int xcd = bx & 7, ii = bx >> 3;
    int w = (xcd < r) ? (xcd * (q + 1) + ii) : (r * (q + 1) + (xcd - r) * q + ii);
    int n0 = (w % NTt) << 7;
    int m0 = (w / NTt) << 7;
    if (m0 >= cnt) return;

    const ushort* WH = WHg + (size_t)e * Ktot * N;
    const ushort* WL = WLg + (size_t)e * Ktot * N;
    const float* bias = biasg + (size_t)e * N;
    C += (size_t)kh * pstride;
    int K = Ktot / KS;
    int koff = kh * K;

    // fragment-ordered LDS: [frag][lane*8 bf16], frag stride 528 ushorts
    __shared__ __align__(16) ushort Ah[8][528], Al[8][528], Bh[8][528], Bl[8][528];

    int tid = threadIdx.x;
    int lane = tid & 63, wid = tid >> 6;
    int wr = wid >> 1, wc = wid & 1;

    // A staging: thread -> row ar (0..127), k-half ah
    int ar = tid >> 1, ah = tid & 1;
    const float* arow;
    {
        int p = m0 + ar;
        int g = (MODE == 0) ? p : rowmap[e * N_TOK + (p < cnt ? p : 0)];
        arow = A + (size_t)g * Ktot;
    }
    int afrag = ar >> 4;
    int alm = ar & 15;

    // B staging: thread -> frag bnf (0..7), same row, two 16B k-chunks
    int bnf = tid >> 5, bsub = tid & 31;
    int brow = n0 + bnf * 16 + (bsub & 15);
    int bkp  = 8 * (bsub >> 4);   // 0 or 8
    const ushort* bhrow = WH + (size_t)brow * Ktot + koff + bkp;
    const ushort* blrow = WL + (size_t)brow * Ktot + koff + bkp;

    f32x4 acc[4][4];
#pragma unroll
    for (int i = 0; i < 4; ++i)
#pragma unroll
        for (int j = 0; j < 4; ++j) acc[i][j] = (f32x4){0.f, 0.f, 0.f, 0.f};

    float fa[16];
    uint4 vbh0, vbh1, vbl0, vbl1;

    auto load_tile = [&](int k0) {
        const float* s = arow + koff + k0 + ah * 16;
        *(float4*)&fa[0]  = *(const float4*)(s);
        *(float4*)&fa[4]  = *(const float4*)(s + 4);
        *(float4*)&fa[8]  = *(const float4*)(s + 8);
        *(float4*)&fa[12] = *(const float4*)(s + 12);
        vbh0 = *(const uint4*)(bhrow + k0);
        vbh1 = *(const uint4*)(bhrow + k0 + 16);
        vbl0 = *(const uint4*)(blrow + k0);
        vbl1 = *(const uint4*)(blrow + k0 + 16);
    };
    auto stage_write = [&]() {
#pragma unroll
        for (int grp = 0; grp < 2; ++grp) {
            uint hv[4], lv[4];
#pragma unroll
            for (int jj = 0; jj < 4; ++jj) {
                float v0 = fa[grp * 8 + jj * 2], v1 = fa[grp * 8 + jj * 2 + 1];
                ushort h0 = bf_rne(v0), h1 = bf_rne(v1);
                ushort l0 = bf_rne(v0 - bf_f(h0)), l1 = bf_rne(v1 - bf_f(h1));
                hv[jj] = (uint)h0 | ((uint)h1 << 16);
                lv[jj] = (uint)l0 | ((uint)l1 << 16);
            }
            int l = (ah * 2 + grp) * 16 + alm;
            *(uint4*)&Ah[afrag][l * 8] = make_uint4(hv[0], hv[1], hv[2], hv[3]);
            *(uint4*)&Al[afrag][l * 8] = make_uint4(lv[0], lv[1], lv[2], lv[3]);
        }
        *(uint4*)&Bh[bnf][bsub * 8]        = vbh0;
        *(uint4*)&Bh[bnf][(bsub + 32) * 8] = vbh1;
        *(uint4*)&Bl[bnf][bsub * 8]        = vbl0;
        *(uint4*)&Bl[bnf][(bsub + 32) * 8] = vbl1;
    };

    int nt = K >> 5;
    load_tile(0);
    stage_write();
    __syncthreads();

    for (int t = 0; t < nt; ++t) {
        bool more = (t + 1 < nt);
        if (more) load_tile((t + 1) << 5);   // issue loads; hide under compute
        // ---- compute: cache B frags, stream A frags, 3 MFMA per pair
        bf16x8 bhv[4], blv[4];
#pragma unroll
        for (int nf = 0; nf < 4; ++nf) {
            int fb = wc * 4 + nf;
            bhv[nf] = *(const bf16x8*)&Bh[fb][lane * 8];
            blv[nf] = *(const bf16x8*)&Bl[fb][lane * 8];
        }
#pragma unroll
        for (int mf = 0; mf < 4; ++mf) {
            int fa2 = wr * 4 + mf;
            bf16x8 a_h = *(const bf16x8*)&Ah[fa2][lane * 8];
            bf16x8 a_l = *(const bf16x8*)&Al[fa2][lane * 8];
#pragma unroll
            for (int nf = 0; nf < 4; ++nf) {
                acc[mf][nf] = __builtin_amdgcn_mfma_f32_16x16x32_bf16(a_h, bhv[nf], acc[mf][nf], 0, 0, 0);
                acc[mf][nf] = __builtin_amdgcn_mfma_f32_16x16x32_bf16(a_h, blv[nf], acc[mf][nf], 0, 0, 0);
                acc[mf][nf] = __builtin_amdgcn_mfma_f32_16x16x32_bf16(a_l, bhv[nf], acc[mf][nf], 0, 0, 0);
            }
        }
        if (more) {
            __syncthreads();   // all readers of current tile done
            stage_write();
            __syncthreads();   // next tile visible
        }
    }

    // ---- epilogue: C/D layout col=lane&15, row=(lane>>4)*4+reg (m89-verified)
    int lr = lane >> 4, lc = lane & 15;
    float bv[4];
#pragma unroll
    for (int nf = 0; nf < 4; ++nf)
        bv[nf] = (kh == 0) ? bias[n0 + wc * 64 + nf * 16 + lc] : 0.f;
#pragma unroll
    for (int mf = 0; mf < 4; ++mf) {
#pragma unroll
        for (int rr = 0; rr < 4; ++rr) {
            int pr = m0 + wr * 64 + mf * 16 + lr * 4 + rr;
            if (MODE != 0 && pr >= cnt) continue;
            size_t orow = (MODE == 0) ? (size_t)pr : (size_t)outmap[e * N_TOK + pr];
            float* crow = C + orow * (size_t)N + n0 + wc * 64 + lc;
#pragma unroll
            for (int nf = 0; nf < 4; ++nf) {
                float v = acc[mf][nf][rr] + bv[nf];
                if (MODE == 1) {
                    float u = 0.7978845608028654f * (v + 0.044715f * v * v * v);
                    v = 0.5f * v * (1.f + tanhf(u));
                }
                crow[nf * 16] = v;
            }
        }
    }
}

// ---------------------------------------------------------------------------
// mod = silu(c) @ adaln_w + adaln_b      (8 x 4608)
__global__ void adaln_kernel(const float* __restrict__ c, const float* __restrict__ w,
                             const float* __restrict__ bias, float* __restrict__ mod) {
    __shared__ float sc[D_];
    int b = blockIdx.y;
    int j = blockIdx.x * 256 + threadIdx.x;
    for (int d = threadIdx.x; d < D_; d += 256) {
        float v = c[b * D_ + d];
        sc[d] = v / (1.f + __expf(-v));
    }
    __syncthreads();
    float acc = bias[j];
    for (int d = 0; d < D_; ++d)
        acc += sc[d] * w[(size_t)d * (4 * D_) + j];
    mod[b * (4 * D_) + j] = acc;
}

// ---------------------------------------------------------------------------
// LayerNorm (biased var, eps=1e-6); optionally apply adaLN modulation.
__global__ void ln_kernel(const float* __restrict__ x, const float* __restrict__ mod,
                          float* __restrict__ out, int use_mod) {
    int n = blockIdx.x;
    int b = n / S_;
    const float* xr = x + (size_t)n * D_;
    float s = 0.f, s2 = 0.f;
    for (int d = threadIdx.x; d < D_; d += 256) {
        float v = xr[d];
        s += v; s2 += v * v;
    }
    for (int off = 32; off > 0; off >>= 1) {
        s  += __shfl_down(s,  off);
        s2 += __shfl_down(s2, off);
    }
    __shared__ float wsum[4], wsum2[4], stats[2];
    int wid = threadIdx.x >> 6, lane = threadIdx.x & 63;
    if (lane == 0) { wsum[wid] = s; wsum2[wid] = s2; }
    __syncthreads();
    if (threadIdx.x == 0) {
        float ts = 0.f, ts2 = 0.f;
        for (int i = 0; i < 4; ++i) { ts += wsum[i]; ts2 += wsum2[i]; }
        float m = ts / D_;
        float var = ts2 / D_ - m * m;
        stats[0] = m; stats[1] = rsqrtf(var + 1e-6f);
    }
    __syncthreads();
    float m = stats[0], inv = stats[1];
    for (int d = threadIdx.x; d < D_; d += 256) {
        float v = (xr[d] - m) * inv;
        if (use_mod)
            v = v * (1.f + mod[b * (4 * D_) + D_ + d]) + mod[b * (4 * D_) + d];
        out[(size_t)n * D_ + d] = v;
    }
}

// ---------------------------------------------------------------------------
// Attention v2: block = (q-tile of 32, head, batch) -> grid (8,16,8), 256 thr.
// Row-major LDS tiles with odd-mod-32 pads (77) for conflict-free scalar reads;
// Pe stride 257 (==1 mod 32); wave-parallel softmax; PV micro-tile 2q x 4dd.
// All LDS arrays explicitly 16B-aligned (float4 LDS ops require it).
__global__ __launch_bounds__(256) void attn_kernel(const float* __restrict__ qkv,
                                                   float* __restrict__ o) {
    int qt = blockIdx.x;   // 0..7
    int hh = blockIdx.y;   // 0..15
    int b  = blockIdx.z;   // 0..7
    __shared__ __align__(16) float Pe[32][257];   // raw scores, then exp'd probs
    __shared__ __align__(16) float Qs[32][77];
    __shared__ __align__(16) float Ks[32][77];
    __shared__ __align__(16) float Vs[32][76];
    __shared__ __align__(16) float sm[8][32];
    __shared__ __align__(16) float rinv[32];
    int t = threadIdx.x;
    const float scale = 0.11785113019775793f;  // 72^-0.5

    // ---- stage Q tile (32 rows x 72), coalesced float4 reads, scalar LDS writes
    for (int i = t; i < 576; i += 256) {
        int r = i / 18, quad = i % 18;
        int n = b * S_ + qt * 32 + r;
        float4 v = *(const float4*)&qkv[(size_t)n * 3456 + hh * HD + quad * 4];
        Qs[r][quad * 4 + 0] = v.x; Qs[r][quad * 4 + 1] = v.y;
        Qs[r][quad * 4 + 2] = v.z; Qs[r][quad * 4 + 3] = v.w;
    }

    // ---- QK^T: 8 key-chunks of 32; thread = (q-row ty, k-quad tx)
    int tx = t & 7, ty = t >> 3;
    for (int c = 0; c < 8; ++c) {
        __syncthreads();   // Qs ready (c==0) / prev chunk's readers done
        for (int i = t; i < 576; i += 256) {
            int r = i / 18, quad = i % 18;
            int n = b * S_ + c * 32 + r;
            float4 v = *(const float4*)&qkv[(size_t)n * 3456 + D_ + hh * HD + quad * 4];
            Ks[r][quad * 4 + 0] = v.x; Ks[r][quad * 4 + 1] = v.y;
            Ks[r][quad * 4 + 2] = v.z; Ks[r][quad * 4 + 3] = v.w;
        }
        __syncthreads();
        float a0 = 0.f, a1 = 0.f, a2 = 0.f, a3 = 0.f;
        const float* q_r = &Qs[ty][0];
        const float* k0r = &Ks[tx * 4 + 0][0];
        const float* k1r = &Ks[tx * 4 + 1][0];
        const float* k2r = &Ks[tx * 4 + 2][0];
        const float* k3r = &Ks[tx * 4 + 3][0];
#pragma unroll 8
        for (int dd = 0; dd < HD; ++dd) {
            float qv = q_r[dd];
            a0 += qv * k0r[dd]; a1 += qv * k1r[dd];
            a2 += qv * k2r[dd]; a3 += qv * k3r[dd];
        }
        Pe[ty][c * 32 + tx * 4 + 0] = a0 * scale;
        Pe[ty][c * 32 + tx * 4 + 1] = a1 * scale;
        Pe[ty][c * 32 + tx * 4 + 2] = a2 * scale;
        Pe[ty][c * 32 + tx * 4 + 3] = a3 * scale;
    }
    __syncthreads();

    // ---- softmax: 32 rows x 8 segments, fully parallel
    int r = t & 31, oct = t >> 5;
    float m = -1e30f;
#pragma unroll 8
    for (int k = 0; k < 32; ++k) m = fmaxf(m, Pe[r][oct * 32 + k]);
    sm[oct][r] = m;
    __syncthreads();
    float mm = sm[0][r];
#pragma unroll
    for (int i = 1; i < 8; ++i) mm = fmaxf(mm, sm[i][r]);
    __syncthreads();   // all reads of sm(max) done before reuse for sums
    float s = 0.f;
#pragma unroll 8
    for (int k = 0; k < 32; ++k) {
        float e = __expf(Pe[r][oct * 32 + k] - mm);
        Pe[r][oct * 32 + k] = e;
        s += e;
    }
    sm[oct][r] = s;
    __syncthreads();
    if (oct == 0) {
        float ts = 0.f;
#pragma unroll
        for (int i = 0; i < 8; ++i) ts += sm[i][r];
        rinv[r] = 1.f / ts;
    }

    // ---- PV: main thread = (q-pair qg, dd-quad dq) covers dd 0..63;
    //      tail (wave 0) = (q tq, dd-quad 16/17) covers dd 64..71
    int dq = t & 15, qg = t >> 4;
    int tq = t & 31, tquad = 16 + (t >> 5);
    float4 acc0 = {0.f, 0.f, 0.f, 0.f}, acc1 = {0.f, 0.f, 0.f, 0.f};
    float4 acct = {0.f, 0.f, 0.f, 0.f};
    for (int c = 0; c < 8; ++c) {
        __syncthreads();   // exp writes (c==0) / prev chunk readers done
        for (int i = t; i < 576; i += 256) {
            int rr = i / 18, quad = i % 18;
            int n = b * S_ + c * 32 + rr;
            float4 v = *(const float4*)&qkv[(size_t)n * 3456 + 2 * D_ + hh * HD + quad * 4];
            *(float4*)&Vs[rr][quad * 4] = v;
        }
        __syncthreads();
#pragma unroll 4
        for (int j = 0; j < 32; ++j) {
            float4 v4 = *(const float4*)&Vs[j][dq * 4];
            float p0 = Pe[qg * 2 + 0][c * 32 + j];
            float p1 = Pe[qg * 2 + 1][c * 32 + j];
            acc0.x += p0 * v4.x; acc0.y += p0 * v4.y;
            acc0.z += p0 * v4.z; acc0.w += p0 * v4.w;
            acc1.x += p1 * v4.x; acc1.y += p1 * v4.y;
            acc1.z += p1 * v4.z; acc1.w += p1 * v4.w;
        }
        if (t < 64) {
#pragma unroll 4
            for (int j = 0; j < 32; ++j) {
                float4 v4 = *(const float4*)&Vs[j][tquad * 4];
                float p = Pe[tq][c * 32 + j];
                acct.x += p * v4.x; acct.y += p * v4.y;
                acct.z += p * v4.z; acct.w += p * v4.w;
            }
        }
    }

    // ---- write O
    {
        int n0 = b * S_ + qt * 32;
        float ri0 = rinv[qg * 2 + 0], ri1 = rinv[qg * 2 + 1];
        float4 o0, o1;
        o0.x = acc0.x * ri0; o0.y = acc0.y * ri0; o0.z = acc0.z * ri0; o0.w = acc0.w * ri0;
        o1.x = acc1.x * ri1; o1.y = acc1.y * ri1; o1.z = acc1.z * ri1; o1.w = acc1.w * ri1;
        *(float4*)&o[(size_t)(n0 + qg * 2 + 0) * D_ + hh * HD + dq * 4] = o0;
        *(float4*)&o[(size_t)(n0 + qg * 2 + 1) * D_ + hh * HD + dq * 4] = o1;
        if (t < 64) {
            float rit = rinv[tq];
            float4 ot;
            ot.x = acct.x * rit; ot.y = acct.y * rit; ot.z = acct.z * rit; ot.w = acct.w * rit;
            *(float4*)&o[(size_t)(n0 + tq) * D_ + hh * HD + tquad * 4] = ot;
        }
    }
}

// ---------------------------------------------------------------------------
// xa = x + gate_msa * (o2A + o2B)    (proj split-K partials)
__global__ void residual1(const float* __restrict__ x, const float* __restrict__ o2a,
                          const float* __restrict__ o2b,
                          const float* __restrict__ mod, float* __restrict__ xa) {
    int i = blockIdx.x * 256 + threadIdx.x;
    int n = i / D_, d = i % D_;
    int b = n / S_;
    xa[i] = x[i] + mod[b * (4 * D_) + 2 * D_ + d] * (o2a[i] + o2b[i]);
}

// ---------------------------------------------------------------------------
// Router: logits = nx @ gate_w + gate_b; top-2 + softmax; build expert lists.
__global__ void router_kernel(const float* __restrict__ nx, const float* __restrict__ gw,
                              const float* __restrict__ gb, int* __restrict__ counts,
                              int* __restrict__ etok, int* __restrict__ eslot,
                              int* __restrict__ tslot, float* __restrict__ tscore) {
    int n = blockIdx.x;
    int lane = threadIdx.x;
    float acc[E_] = {};
    for (int d = lane; d < D_; d += 64) {
        float v = nx[(size_t)n * D_ + d];
#pragma unroll
        for (int e = 0; e < E_; ++e) acc[e] += v * gw[d * E_ + e];
    }
#pragma unroll
    for (int e = 0; e < E_; ++e)
        for (int off = 32; off > 0; off >>= 1) acc[e] += __shfl_down(acc[e], off);
    if (lane == 0) {
        float lg[E_];
#pragma unroll
        for (int e = 0; e < E_; ++e) lg[e] = acc[e] + gb[e];
        int i0 = 0;
        for (int e = 1; e < E_; ++e) if (lg[e] > lg[i0]) i0 = e;
        int i1 = -1;
        for (int e = 0; e < E_; ++e) {
            if (e == i0) continue;
            if (i1 < 0 || lg[e] > lg[i1]) i1 = e;
        }
        float e1 = __expf(lg[i1] - lg[i0]);
        float p0 = 1.f / (1.f + e1), p1 = e1 / (1.f + e1);
        int p, slot;
        p = atomicAdd(&counts[i0], 1);
        slot = atomicAdd(&counts[8], 1);
        etok[i0 * N_TOK + p] = n; eslot[i0 * N_TOK + p] = slot;
        tslot[n * 2 + 0] = slot; tscore[n * 2 + 0] = p0;
        p = atomicAdd(&counts[i1], 1);
        slot = atomicAdd(&counts[8], 1);
        etok[i1 * N_TOK + p] = n; eslot[i1 * N_TOK + p] = slot;
        tslot[n * 2 + 1] = slot; tscore[n * 2 + 1] = p1;
    }
}

// ---------------------------------------------------------------------------
// out = xa + gate_mlp * (s0*(eoA+eoB)[slot0] + s1*(eoA+eoB)[slot1])
__global__ void combine_kernel(const float* __restrict__ xa, const float* __restrict__ eoa,
                               const float* __restrict__ eob,
                               const float* __restrict__ mod, const int* __restrict__ tslot,
                               const float* __restrict__ tscore, float* __restrict__ out) {
    int i = blockIdx.x * 256 + threadIdx.x;
    int n = i / D_, d = i % D_, b = n / S_;
    int s0 = tslot[n * 2 + 0], s1 = tslot[n * 2 + 1];
    float moe = tscore[n * 2 + 0] * (eoa[(size_t)s0 * D_ + d] + eob[(size_t)s0 * D_ + d]) +
                tscore[n * 2 + 1] * (eoa[(size_t)s1 * D_ + d] + eob[(size_t)s1 * D_ + d]);
    out[i] = xa[i] + mod[b * (4 * D_) + 3 * D_ + d] * moe;
}

__global__ void zero_counts(int* counts) {
    if (threadIdx.x < 16) counts[threadIdx.x] = 0;
}

// ---------------------------------------------------------------------------
extern "C" void kernel_launch(void* const* d_in, const int* in_sizes, int n_in,
                              void* d_out, int out_size, void* d_ws, size_t ws_size,
                              hipStream_t stream) {
    (void)in_sizes; (void)n_in; (void)out_size; (void)ws_size;
    const float* x       = (const float*)d_in[0];
    const float* c       = (const float*)d_in[1];
    const float* qkv_w   = (const float*)d_in[2];
    const float* qkv_b   = (const float*)d_in[3];
    const float* proj_w  = (const float*)d_in[4];
    const float* proj_b  = (const float*)d_in[5];
    const float* adaln_w = (const float*)d_in[6];
    const float* adaln_b = (const float*)d_in[7];
    const float* gate_w  = (const float*)d_in[8];
    const float* gate_b  = (const float*)d_in[9];
    const float* w1      = (const float*)d_in[10];
    const float* b1      = (const float*)d_in[11];
    const float* w2      = (const float*)d_in[12];
    const float* b2      = (const float*)d_in[13];

    float* ws = (float*)d_ws;
    float* mod  = ws;                         //      36864
    float* xa   = ws + 36864;                 //  2,359,296
    float* buf1 = ws + 2396160;               //  2,359,296  (h, later nx)
    float* qkvb = ws + 4755456;               //  7,077,888
    float* atto = ws + 11833344;              //  2,359,296
    float* o2   = ws + 14192640;              //  2,359,296  (o2A; o2B contiguous after)
    // o2B = ws + 16551936 (inside future-h1 region; dead before moe1 writes h1)
    float* h1   = ws + 4755456;               // 18,874,368 (after qkv/atto/o2 dead)
    float* eo   = ws + 23629824;              //  4,718,592 (eoA) -> ends 28,348,416
    int*   counts = (int*)(ws + 28348416);    // 16
    int*   etok   = counts + 16;              // 16384
    int*   eslot  = etok + 16384;             // 16384
    int*   tslot  = eslot + 16384;            // 4096
    float* tscore = (float*)(tslot + 4096);   // 4096  -> ends 28,389,392 floats

    // bf16 hi/lo transposed weight planes (ushort), after the fp32 region
    ushort* wt = (ushort*)(ws + 28389392);
    ushort* qkvT_hi = wt;                       // 1152*3456 = 3,981,312
    ushort* qkvT_lo = qkvT_hi + 3981312;
    ushort* projT_hi = qkvT_lo + 3981312;       // 1152*1152 = 1,327,104
    ushort* projT_lo = projT_hi + 1327104;
    ushort* w1T_hi = projT_lo + 1327104;        // 8*1152*4608 = 42,467,328
    ushort* w1T_lo = w1T_hi + 42467328;
    ushort* w2T_hi = w1T_lo + 42467328;         // 8*4608*1152 = 42,467,328
    ushort* w2T_lo = w2T_hi + 42467328;
    // eoB overlays the (then-dead) qkvT/projT planes: float offset 28,389,392.
    // pstride for moe2 = 28,389,392 - 23,629,824 = 4,759,568 elements.
    float* eoB = ws + 28389392;

    zero_counts<<<1, 64, 0, stream>>>(counts);
    // weight transpose+split
    wsplit<<<dim3(3456 / 32, 1152 / 32, 1), 256, 0, stream>>>(qkv_w, qkvT_hi, qkvT_lo, 1152, 3456);
    wsplit<<<dim3(1152 / 32, 1152 / 32, 1), 256, 0, stream>>>(proj_w, projT_hi, projT_lo, 1152, 1152);
    wsplit<<<dim3(4608 / 32, 1152 / 32, E_), 256, 0, stream>>>(w1, w1T_hi, w1T_lo, 1152, 4608);
    wsplit<<<dim3(1152 / 32, 4608 / 32, E_), 256, 0, stream>>>(w2, w2T_hi, w2T_lo, 4608, 1152);

    adaln_kernel<<<dim3(18, 8), 256, 0, stream>>>(c, adaln_w, adaln_b, mod);
    ln_kernel<<<N_TOK, 256, 0, stream>>>(x, mod, buf1, 1);
    // qkv: 27 nt x 16 mt = 432 blocks (div 8)
    mfma_gemm<0, 1><<<dim3(432, 1, 1), 256, 0, stream>>>(
        buf1, qkvT_hi, qkvT_lo, qkv_b, qkvb, N_TOK, 3456, D_, 0ULL,
        nullptr, nullptr, nullptr);
    attn_kernel<<<dim3(8, H_, B_), 256, 0, stream>>>(qkvb, atto);
    // proj: 9 nt x 16 mt = 144 blocks, split-K x2 -> o2A / o2B contiguous
    mfma_gemm<0, 2><<<dim3(144, 1, 2), 256, 0, stream>>>(
        atto, projT_hi, projT_lo, proj_b, o2, N_TOK, D_, D_, 2359296ULL,
        nullptr, nullptr, nullptr);
    residual1<<<(N_TOK * D_) / 256, 256, 0, stream>>>(x, o2, o2 + 2359296, mod, xa);
    ln_kernel<<<N_TOK, 256, 0, stream>>>(xa, nullptr, buf1, 0);
    router_kernel<<<N_TOK, 64, 0, stream>>>(buf1, gate_w, gate_b, counts, etok, eslot,
                                            tslot, tscore);
    // moe1: 36 nt x 16 mt = 576 blocks/expert (active ~144), gelu -> no split-K
    mfma_gemm<1, 1><<<dim3(576, 1, E_), 256, 0, stream>>>(
        buf1, w1T_hi, w1T_lo, b1, h1, N_TOK, MLPH, D_, 0ULL,
        counts, etok, eslot);
    // moe2: 9 nt x 16 mt = 144 blocks/expert, split-K x2 -> eoA / eoB
    mfma_gemm<2, 2><<<dim3(144, 1, E_ * 2), 256, 0, stream>>>(
        h1, w2T_hi, w2T_lo, b2, eo, N_TOK, D_, MLPH, 4759568ULL,
        counts, eslot, eslot);
    combine_kernel<<<(N_TOK * D_) / 256, 256, 0, stream>>>(xa, eo, eoB, mod, tslot,
                                                           tscore, (float*)d_out);
}

// Round 8
// 1362.333 us; speedup vs baseline: 2.0349x; 1.0068x over previous
//
#include <hip/hip_runtime.h>
#include <math.h>

#define D_    1152
#define H_    16
#define HD    72
#define E_    8
#define MLPH  4608
#define B_    8
#define S_    256
#define N_TOK 2048

typedef __attribute__((ext_vector_type(8))) short bf16x8;
typedef __attribute__((ext_vector_type(4))) float f32x4;

__device__ __forceinline__ ushort bf_rne(float x) {
    uint u = __float_as_uint(x);
    return (ushort)((u + 0x7FFFu + ((u >> 16) & 1u)) >> 16);
}
__device__ __forceinline__ float bf_f(ushort h) {
    return __uint_as_float(((uint)h) << 16);
}

// ---------------------------------------------------------------------------
// Transpose + split: W[K][N] fp32  ->  hi/lo bf16 planes [N][K]
// grid (N/32, K/32, E), block 256
__global__ __launch_bounds__(256) void wsplit(const float* __restrict__ src,
                                              ushort* __restrict__ hi,
                                              ushort* __restrict__ lo,
                                              int K, int N) {
    size_t off = (size_t)blockIdx.z * K * N;
    src += off; hi += off; lo += off;
    __shared__ float t[32][33];
    int k0 = blockIdx.y * 32, n0 = blockIdx.x * 32;
    int r = threadIdx.x >> 3, cq = (threadIdx.x & 7) * 4;
    float4 v = *(const float4*)&src[(size_t)(k0 + r) * N + n0 + cq];
    t[r][cq + 0] = v.x; t[r][cq + 1] = v.y; t[r][cq + 2] = v.z; t[r][cq + 3] = v.w;
    __syncthreads();
    int n = threadIdx.x >> 3, kq = (threadIdx.x & 7) * 4;
    ushort4 hv, lv;
    {
        float f0 = t[kq + 0][n], f1 = t[kq + 1][n], f2 = t[kq + 2][n], f3 = t[kq + 3][n];
        hv.x = bf_rne(f0); lv.x = bf_rne(f0 - bf_f(hv.x));
        hv.y = bf_rne(f1); lv.y = bf_rne(f1 - bf_f(hv.y));
        hv.z = bf_rne(f2); lv.z = bf_rne(f2 - bf_f(hv.z));
        hv.w = bf_rne(f3); lv.w = bf_rne(f3 - bf_f(hv.w));
    }
    size_t o = (size_t)(n0 + n) * K + k0 + kq;
    *(ushort4*)&hi[o] = hv;
    *(ushort4*)&lo[o] = lv;
}

// ---------------------------------------------------------------------------
// MFMA GEMM, bf16x3 split (fp32-accurate): C = A @ W + bias.
// Tile 128x128, BK=32, 256 threads = 4 waves in 2x2, wave tile 64x64.
// v3: split-K (KS) with partials at C + kh*pstride (bias on kh==0 only),
//     register prefetch of tile t+1, bijective XCD-chunked swizzle over the
//     ACTIVE grid. MSWZ=0: n-fastest (A-panel L2 reuse); MSWZ=1: m-fastest
//     (B-panel L2 reuse — for moe1 where B is the big re-read operand).
//   MODE 0: dense   MODE 1: moe up (gelu; KS must be 1)   MODE 2: moe down
template<int MODE, int KS, int MSWZ>
__global__ __launch_bounds__(256) void mfma_gemm(
    const float* __restrict__ A, const ushort* __restrict__ WHg,
    const ushort* __restrict__ WLg, const float* __restrict__ biasg,
    float* __restrict__ C, int M, int N, int Ktot,
    unsigned long long pstride,
    const int* __restrict__ counts, const int* __restrict__ rowmap,
    const int* __restrict__ outmap) {
    int zz = (int)blockIdx.z;
    int kh = (KS == 1) ? 0 : (zz % KS);
    int e  = (KS == 1) ? zz : (zz / KS);
    int cnt = (MODE == 0) ? M : counts[e];
    int NTt = N >> 7;
    int MTa = (MODE == 0) ? (M >> 7) : ((cnt + 127) >> 7);
    int nb = NTt * MTa;
    int bx = (int)blockIdx.x;
    if (bx >= nb) return;
    // bijective XCD-chunked swizzle (bx%8 -> XCD phase; grid.x % 8 == 0)
    int q = nb >> 3, r = nb & 7;
    int xcd = bx & 7, ii = bx >> 3;
    int w = (xcd < r) ? (xcd * (q + 1) + ii) : (r * (q + 1) + (xcd - r) * q + ii);
    int n0, m0;
    if (MSWZ) { n0 = (w / MTa) << 7; m0 = (w % MTa) << 7; }
    else      { n0 = (w % NTt) << 7; m0 = (w / NTt) << 7; }
    if (m0 >= cnt) return;

    const ushort* WH = WHg + (size_t)e * Ktot * N;
    const ushort* WL = WLg + (size_t)e * Ktot * N;
    const float* bias = biasg + (size_t)e * N;
    C += (size_t)kh * pstride;
    int K = Ktot / KS;
    int koff = kh * K;

    // fragment-ordered LDS: [frag][lane*8 bf16], frag stride 528 ushorts
    __shared__ __align__(16) ushort Ah[8][528], Al[8][528], Bh[8][528], Bl[8][528];

    int tid = threadIdx.x;
    int lane = tid & 63, wid = tid >> 6;
    int wr = wid >> 1, wc = wid & 1;

    // A staging: thread -> row ar (0..127), k-half ah
    int ar = tid >> 1, ah = tid & 1;
    const float* arow;
    {
        int p = m0 + ar;
        int g = (MODE == 0) ? p : rowmap[e * N_TOK + (p < cnt ? p : 0)];
        arow = A + (size_t)g * Ktot;
    }
    int afrag = ar >> 4;
    int alm = ar & 15;

    // B staging: thread -> frag bnf (0..7), same row, two 16B k-chunks
    int bnf = tid >> 5, bsub = tid & 31;
    int brow = n0 + bnf * 16 + (bsub & 15);
    int bkp  = 8 * (bsub >> 4);   // 0 or 8
    const ushort* bhrow = WH + (size_t)brow * Ktot + koff + bkp;
    const ushort* blrow = WL + (size_t)brow * Ktot + koff + bkp;

    f32x4 acc[4][4];
#pragma unroll
    for (int i = 0; i < 4; ++i)
#pragma unroll
        for (int j = 0; j < 4; ++j) acc[i][j] = (f32x4){0.f, 0.f, 0.f, 0.f};

    float fa[16];
    uint4 vbh0, vbh1, vbl0, vbl1;

    auto load_tile = [&](int k0) {
        const float* s = arow + koff + k0 + ah * 16;
        *(float4*)&fa[0]  = *(const float4*)(s);
        *(float4*)&fa[4]  = *(const float4*)(s + 4);
        *(float4*)&fa[8]  = *(const float4*)(s + 8);
        *(float4*)&fa[12] = *(const float4*)(s + 12);
        vbh0 = *(const uint4*)(bhrow + k0);
        vbh1 = *(const uint4*)(bhrow + k0 + 16);
        vbl0 = *(const uint4*)(blrow + k0);
        vbl1 = *(const uint4*)(blrow + k0 + 16);
    };
    auto stage_write = [&]() {
#pragma unroll
        for (int grp = 0; grp < 2; ++grp) {
            uint hv[4], lv[4];
#pragma unroll
            for (int jj = 0; jj < 4; ++jj) {
                float v0 = fa[grp * 8 + jj * 2], v1 = fa[grp * 8 + jj * 2 + 1];
                ushort h0 = bf_rne(v0), h1 = bf_rne(v1);
                ushort l0 = bf_rne(v0 - bf_f(h0)), l1 = bf_rne(v1 - bf_f(h1));
                hv[jj] = (uint)h0 | ((uint)h1 << 16);
                lv[jj] = (uint)l0 | ((uint)l1 << 16);
            }
            int l = (ah * 2 + grp) * 16 + alm;
            *(uint4*)&Ah[afrag][l * 8] = make_uint4(hv[0], hv[1], hv[2], hv[3]);
            *(uint4*)&Al[afrag][l * 8] = make_uint4(lv[0], lv[1], lv[2], lv[3]);
        }
        *(uint4*)&Bh[bnf][bsub * 8]        = vbh0;
        *(uint4*)&Bh[bnf][(bsub + 32) * 8] = vbh1;
        *(uint4*)&Bl[bnf][bsub * 8]        = vbl0;
        *(uint4*)&Bl[bnf][(bsub + 32) * 8] = vbl1;
    };

    int nt = K >> 5;
    load_tile(0);
    stage_write();
    __syncthreads();

    for (int t = 0; t < nt; ++t) {
        bool more = (t + 1 < nt);
        if (more) load_tile((t + 1) << 5);   // issue loads; hide under compute
        // ---- compute: cache B frags, stream A frags, 3 MFMA per pair
        bf16x8 bhv[4], blv[4];
#pragma unroll
        for (int nf = 0; nf < 4; ++nf) {
            int fb = wc * 4 + nf;
            bhv[nf] = *(const bf16x8*)&Bh[fb][lane * 8];
            blv[nf] = *(const bf16x8*)&Bl[fb][lane * 8];
        }
#pragma unroll
        for (int mf = 0; mf < 4; ++mf) {
            int fa2 = wr * 4 + mf;
            bf16x8 a_h = *(const bf16x8*)&Ah[fa2][lane * 8];
            bf16x8 a_l = *(const bf16x8*)&Al[fa2][lane * 8];
#pragma unroll
            for (int nf = 0; nf < 4; ++nf) {
                acc[mf][nf] = __builtin_amdgcn_mfma_f32_16x16x32_bf16(a_h, bhv[nf], acc[mf][nf], 0, 0, 0);
                acc[mf][nf] = __builtin_amdgcn_mfma_f32_16x16x32_bf16(a_h, blv[nf], acc[mf][nf], 0, 0, 0);
                acc[mf][nf] = __builtin_amdgcn_mfma_f32_16x16x32_bf16(a_l, bhv[nf], acc[mf][nf], 0, 0, 0);
            }
        }
        if (more) {
            __syncthreads();   // all readers of current tile done
            stage_write();
            __syncthreads();   // next tile visible
        }
    }

    // ---- epilogue: C/D layout col=lane&15, row=(lane>>4)*4+reg (m89-verified)
    int lr = lane >> 4, lc = lane & 15;
    float bv[4];
#pragma unroll
    for (int nf = 0; nf < 4; ++nf)
        bv[nf] = (kh == 0) ? bias[n0 + wc * 64 + nf * 16 + lc] : 0.f;
#pragma unroll
    for (int mf = 0; mf < 4; ++mf) {
#pragma unroll
        for (int rr = 0; rr < 4; ++rr) {
            int pr = m0 + wr * 64 + mf * 16 + lr * 4 + rr;
            if (MODE != 0 && pr >= cnt) continue;
            size_t orow = (MODE == 0) ? (size_t)pr : (size_t)outmap[e * N_TOK + pr];
            float* crow = C + orow * (size_t)N + n0 + wc * 64 + lc;
#pragma unroll
            for (int nf = 0; nf < 4; ++nf) {
                float v = acc[mf][nf][rr] + bv[nf];
                if (MODE == 1) {
                    float u = 0.7978845608028654f * (v + 0.044715f * v * v * v);
                    v = 0.5f * v * (1.f + tanhf(u));
                }
                crow[nf * 16] = v;
            }
        }
    }
}

// ---------------------------------------------------------------------------
// mod = silu(c) @ adaln_w + adaln_b      (8 x 4608)
__global__ void adaln_kernel(const float* __restrict__ c, const float* __restrict__ w,
                             const float* __restrict__ bias, float* __restrict__ mod) {
    __shared__ float sc[D_];
    int b = blockIdx.y;
    int j = blockIdx.x * 256 + threadIdx.x;
    for (int d = threadIdx.x; d < D_; d += 256) {
        float v = c[b * D_ + d];
        sc[d] = v / (1.f + __expf(-v));
    }
    __syncthreads();
    float acc = bias[j];
    for (int d = 0; d < D_; ++d)
        acc += sc[d] * w[(size_t)d * (4 * D_) + j];
    mod[b * (4 * D_) + j] = acc;
}

// ---------------------------------------------------------------------------
// LayerNorm (biased var, eps=1e-6); optionally apply adaLN modulation.
__global__ void ln_kernel(const float* __restrict__ x, const float* __restrict__ mod,
                          float* __restrict__ out, int use_mod) {
    int n = blockIdx.x;
    int b = n / S_;
    const float* xr = x + (size_t)n * D_;
    float s = 0.f, s2 = 0.f;
    for (int d = threadIdx.x; d < D_; d += 256) {
        float v = xr[d];
        s += v; s2 += v * v;
    }
    for (int off = 32; off > 0; off >>= 1) {
        s  += __shfl_down(s,  off);
        s2 += __shfl_down(s2, off);
    }
    __shared__ float wsum[4], wsum2[4], stats[2];
    int wid = threadIdx.x >> 6, lane = threadIdx.x & 63;
    if (lane == 0) { wsum[wid] = s; wsum2[wid] = s2; }
    __syncthreads();
    if (threadIdx.x == 0) {
        float ts = 0.f, ts2 = 0.f;
        for (int i = 0; i < 4; ++i) { ts += wsum[i]; ts2 += wsum2[i]; }
        float m = ts / D_;
        float var = ts2 / D_ - m * m;
        stats[0] = m; stats[1] = rsqrtf(var + 1e-6f);
    }
    __syncthreads();
    float m = stats[0], inv = stats[1];
    for (int d = threadIdx.x; d < D_; d += 256) {
        float v = (xr[d] - m) * inv;
        if (use_mod)
            v = v * (1.f + mod[b * (4 * D_) + D_ + d]) + mod[b * (4 * D_) + d];
        out[(size_t)n * D_ + d] = v;
    }
}

// ---------------------------------------------------------------------------
// Attention v2: block = (q-tile of 32, head, batch) -> grid (8,16,8), 256 thr.
// Row-major LDS tiles with odd-mod-32 pads (77) for conflict-free scalar reads;
// Pe stride 257 (==1 mod 32); wave-parallel softmax; PV micro-tile 2q x 4dd.
// All LDS arrays explicitly 16B-aligned (float4 LDS ops require it).
__global__ __launch_bounds__(256) void attn_kernel(const float* __restrict__ qkv,
                                                   float* __restrict__ o) {
    int qt = blockIdx.x;   // 0..7
    int hh = blockIdx.y;   // 0..15
    int b  = blockIdx.z;   // 0..7
    __shared__ __align__(16) float Pe[32][257];   // raw scores, then exp'd probs
    __shared__ __align__(16) float Qs[32][77];
    __shared__ __align__(16) float Ks[32][77];
    __shared__ __align__(16) float Vs[32][76];
    __shared__ __align__(16) float sm[8][32];
    __shared__ __align__(16) float rinv[32];
    int t = threadIdx.x;
    const float scale = 0.11785113019775793f;  // 72^-0.5

    // ---- stage Q tile (32 rows x 72), coalesced float4 reads, scalar LDS writes
    for (int i = t; i < 576; i += 256) {
        int r = i / 18, quad = i % 18;
        int n = b * S_ + qt * 32 + r;
        float4 v = *(const float4*)&qkv[(size_t)n * 3456 + hh * HD + quad * 4];
        Qs[r][quad * 4 + 0] = v.x; Qs[r][quad * 4 + 1] = v.y;
        Qs[r][quad * 4 + 2] = v.z; Qs[r][quad * 4 + 3] = v.w;
    }

    // ---- QK^T: 8 key-chunks of 32; thread = (q-row ty, k-quad tx)
    int tx = t & 7, ty = t >> 3;
    for (int c = 0; c < 8; ++c) {
        __syncthreads();   // Qs ready (c==0) / prev chunk's readers done
        for (int i = t; i < 576; i += 256) {
            int r = i / 18, quad = i % 18;
            int n = b * S_ + c * 32 + r;
            float4 v = *(const float4*)&qkv[(size_t)n * 3456 + D_ + hh * HD + quad * 4];
            Ks[r][quad * 4 + 0] = v.x; Ks[r][quad * 4 + 1] = v.y;
            Ks[r][quad * 4 + 2] = v.z; Ks[r][quad * 4 + 3] = v.w;
        }
        __syncthreads();
        float a0 = 0.f, a1 = 0.f, a2 = 0.f, a3 = 0.f;
        const float* q_r = &Qs[ty][0];
        const float* k0r = &Ks[tx * 4 + 0][0];
        const float* k1r = &Ks[tx * 4 + 1][0];
        const float* k2r = &Ks[tx * 4 + 2][0];
        const float* k3r = &Ks[tx * 4 + 3][0];
#pragma unroll 8
        for (int dd = 0; dd < HD; ++dd) {
            float qv = q_r[dd];
            a0 += qv * k0r[dd]; a1 += qv * k1r[dd];
            a2 += qv * k2r[dd]; a3 += qv * k3r[dd];
        }
        Pe[ty][c * 32 + tx * 4 + 0] = a0 * scale;
        Pe[ty][c * 32 + tx * 4 + 1] = a1 * scale;
        Pe[ty][c * 32 + tx * 4 + 2] = a2 * scale;
        Pe[ty][c * 32 + tx * 4 + 3] = a3 * scale;
    }
    __syncthreads();

    // ---- softmax: 32 rows x 8 segments, fully parallel
    int r = t & 31, oct = t >> 5;
    float m = -1e30f;
#pragma unroll 8
    for (int k = 0; k < 32; ++k) m = fmaxf(m, Pe[r][oct * 32 + k]);
    sm[oct][r] = m;
    __syncthreads();
    float mm = sm[0][r];
#pragma unroll
    for (int i = 1; i < 8; ++i) mm = fmaxf(mm, sm[i][r]);
    __syncthreads();   // all reads of sm(max) done before reuse for sums
    float s = 0.f;
#pragma unroll 8
    for (int k = 0; k < 32; ++k) {
        float e = __expf(Pe[r][oct * 32 + k] - mm);
        Pe[r][oct * 32 + k] = e;
        s += e;
    }
    sm[oct][r] = s;
    __syncthreads();
    if (oct == 0) {
        float ts = 0.f;
#pragma unroll
        for (int i = 0; i < 8; ++i) ts += sm[i][r];
        rinv[r] = 1.f / ts;
    }

    // ---- PV: main thread = (q-pair qg, dd-quad dq) covers dd 0..63;
    //      tail (wave 0) = (q tq, dd-quad 16/17) covers dd 64..71
    int dq = t & 15, qg = t >> 4;
    int tq = t & 31, tquad = 16 + (t >> 5);
    float4 acc0 = {0.f, 0.f, 0.f, 0.f}, acc1 = {0.f, 0.f, 0.f, 0.f};
    float4 acct = {0.f, 0.f, 0.f, 0.f};
    for (int c = 0; c < 8; ++c) {
        __syncthreads();   // exp writes (c==0) / prev chunk readers done
        for (int i = t; i < 576; i += 256) {
            int rr = i / 18, quad = i % 18;
            int n = b * S_ + c * 32 + rr;
            float4 v = *(const float4*)&qkv[(size_t)n * 3456 + 2 * D_ + hh * HD + quad * 4];
            *(float4*)&Vs[rr][quad * 4] = v;
        }
        __syncthreads();
#pragma unroll 4
        for (int j = 0; j < 32; ++j) {
            float4 v4 = *(const float4*)&Vs[j][dq * 4];
            float p0 = Pe[qg * 2 + 0][c * 32 + j];
            float p1 = Pe[qg * 2 + 1][c * 32 + j];
            acc0.x += p0 * v4.x; acc0.y += p0 * v4.y;
            acc0.z += p0 * v4.z; acc0.w += p0 * v4.w;
            acc1.x += p1 * v4.x; acc1.y += p1 * v4.y;
            acc1.z += p1 * v4.z; acc1.w += p1 * v4.w;
        }
        if (t < 64) {
#pragma unroll 4
            for (int j = 0; j < 32; ++j) {
                float4 v4 = *(const float4*)&Vs[j][tquad * 4];
                float p = Pe[tq][c * 32 + j];
                acct.x += p * v4.x; acct.y += p * v4.y;
                acct.z += p * v4.z; acct.w += p * v4.w;
            }
        }
    }

    // ---- write O
    {
        int n0 = b * S_ + qt * 32;
        float ri0 = rinv[qg * 2 + 0], ri1 = rinv[qg * 2 + 1];
        float4 o0, o1;
        o0.x = acc0.x * ri0; o0.y = acc0.y * ri0; o0.z = acc0.z * ri0; o0.w = acc0.w * ri0;
        o1.x = acc1.x * ri1; o1.y = acc1.y * ri1; o1.z = acc1.z * ri1; o1.w = acc1.w * ri1;
        *(float4*)&o[(size_t)(n0 + qg * 2 + 0) * D_ + hh * HD + dq * 4] = o0;
        *(float4*)&o[(size_t)(n0 + qg * 2 + 1) * D_ + hh * HD + dq * 4] = o1;
        if (t < 64) {
            float rit = rinv[tq];
            float4 ot;
            ot.x = acct.x * rit; ot.y = acct.y * rit; ot.z = acct.z * rit; ot.w = acct.w * rit;
            *(float4*)&o[(size_t)(n0 + tq) * D_ + hh * HD + tquad * 4] = ot;
        }
    }
}

// ---------------------------------------------------------------------------
// xa = x + gate_msa * (o2[0]+o2[1]+o2[2]+o2[3])    (proj split-K x4 partials)
__global__ void residual1(const float* __restrict__ x, const float* __restrict__ o2p,
                          const float* __restrict__ mod, float* __restrict__ xa) {
    int i = blockIdx.x * 256 + threadIdx.x;
    int n = i / D_, d = i % D_;
    int b = n / S_;
    float s = o2p[i] + o2p[i + 2359296] + o2p[i + 2 * 2359296] + o2p[i + 3 * 2359296];
    xa[i] = x[i] + mod[b * (4 * D_) + 2 * D_ + d] * s;
}

// ---------------------------------------------------------------------------
// Router: logits = nx @ gate_w + gate_b; top-2 + softmax; build expert lists.
__global__ void router_kernel(const float* __restrict__ nx, const float* __restrict__ gw,
                              const float* __restrict__ gb, int* __restrict__ counts,
                              int* __restrict__ etok, int* __restrict__ eslot,
                              int* __restrict__ tslot, float* __restrict__ tscore) {
    int n = blockIdx.x;
    int lane = threadIdx.x;
    float acc[E_] = {};
    for (int d = lane; d < D_; d += 64) {
        float v = nx[(size_t)n * D_ + d];
#pragma unroll
        for (int e = 0; e < E_; ++e) acc[e] += v * gw[d * E_ + e];
    }
#pragma unroll
    for (int e = 0; e < E_; ++e)
        for (int off = 32; off > 0; off >>= 1) acc[e] += __shfl_down(acc[e], off);
    if (lane == 0) {
        float lg[E_];
#pragma unroll
        for (int e = 0; e < E_; ++e) lg[e] = acc[e] + gb[e];
        int i0 = 0;
        for (int e = 1; e < E_; ++e) if (lg[e] > lg[i0]) i0 = e;
        int i1 = -1;
        for (int e = 0; e < E_; ++e) {
            if (e == i0) continue;
            if (i1 < 0 || lg[e] > lg[i1]) i1 = e;
        }
        float e1 = __expf(lg[i1] - lg[i0]);
        float p0 = 1.f / (1.f + e1), p1 = e1 / (1.f + e1);
        int p, slot;
        p = atomicAdd(&counts[i0], 1);
        slot = atomicAdd(&counts[8], 1);
        etok[i0 * N_TOK + p] = n; eslot[i0 * N_TOK + p] = slot;
        tslot[n * 2 + 0] = slot; tscore[n * 2 + 0] = p0;
        p = atomicAdd(&counts[i1], 1);
        slot = atomicAdd(&counts[8], 1);
        etok[i1 * N_TOK + p] = n; eslot[i1 * N_TOK + p] = slot;
        tslot[n * 2 + 1] = slot; tscore[n * 2 + 1] = p1;
    }
}

// ---------------------------------------------------------------------------
// out = xa + gate_mlp * (s0*sum_kh eo[kh][slot0] + s1*sum_kh eo[kh][slot1])
__global__ void combine_kernel(const float* __restrict__ xa, const float* __restrict__ eop,
                               const float* __restrict__ mod, const int* __restrict__ tslot,
                               const float* __restrict__ tscore, float* __restrict__ out) {
    int i = blockIdx.x * 256 + threadIdx.x;
    int n = i / D_, d = i % D_, b = n / S_;
    int s0 = tslot[n * 2 + 0], s1 = tslot[n * 2 + 1];
    float e0 = 0.f, e1 = 0.f;
#pragma unroll
    for (int kh = 0; kh < 4; ++kh) {
        const float* p = eop + (size_t)kh * 4718592;
        e0 += p[(size_t)s0 * D_ + d];
        e1 += p[(size_t)s1 * D_ + d];
    }
    float moe = tscore[n * 2 + 0] * e0 + tscore[n * 2 + 1] * e1;
    out[i] = xa[i] + mod[b * (4 * D_) + 3 * D_ + d] * moe;
}

__global__ void zero_counts(int* counts) {
    if (threadIdx.x < 16) counts[threadIdx.x] = 0;
}

// ---------------------------------------------------------------------------
extern "C" void kernel_launch(void* const* d_in, const int* in_sizes, int n_in,
                              void* d_out, int out_size, void* d_ws, size_t ws_size,
                              hipStream_t stream) {
    (void)in_sizes; (void)n_in; (void)out_size; (void)ws_size;
    const float* x       = (const float*)d_in[0];
    const float* c       = (const float*)d_in[1];
    const float* qkv_w   = (const float*)d_in[2];
    const float* qkv_b   = (const float*)d_in[3];
    const float* proj_w  = (const float*)d_in[4];
    const float* proj_b  = (const float*)d_in[5];
    const float* adaln_w = (const float*)d_in[6];
    const float* adaln_b = (const float*)d_in[7];
    const float* gate_w  = (const float*)d_in[8];
    const float* gate_b  = (const float*)d_in[9];
    const float* w1      = (const float*)d_in[10];
    const float* b1      = (const float*)d_in[11];
    const float* w2      = (const float*)d_in[12];
    const float* b2      = (const float*)d_in[13];

    float* ws = (float*)d_ws;
    float* mod  = ws;                         //      36864
    float* xa   = ws + 36864;                 //  2,359,296
    float* buf1 = ws + 2396160;               //  2,359,296  (h, later nx)
    float* qkvb = ws + 4755456;               //  7,077,888
    float* atto = ws + 11833344;              //  2,359,296
    float* o2   = ws + 14192640;              //  2,359,296 x4 split-K partials
    //            o2 partials span 14,192,640 .. 23,629,824 (inside future-h1)
    float* h1   = ws + 4755456;               // 18,874,368 (after qkv/atto/o2 dead)
    int*   counts = (int*)(ws + 28348416);    // 16
    int*   etok   = counts + 16;              // 16384
    int*   eslot  = etok + 16384;             // 16384
    int*   tslot  = eslot + 16384;            // 4096
    float* tscore = (float*)(tslot + 4096);   // 4096  -> ends 28,389,392 floats

    // bf16 hi/lo transposed weight planes (ushort), after the fp32 region
    ushort* wt = (ushort*)(ws + 28389392);
    ushort* qkvT_hi = wt;                       // 1152*3456 = 3,981,312
    ushort* qkvT_lo = qkvT_hi + 3981312;
    ushort* projT_hi = qkvT_lo + 3981312;       // 1152*1152 = 1,327,104
    ushort* projT_lo = projT_hi + 1327104;
    ushort* w1T_hi = projT_lo + 1327104;        // 8*1152*4608 = 42,467,328
    ushort* w1T_lo = w1T_hi + 42467328;
    ushort* w2T_hi = w1T_lo + 42467328;         // 8*4608*1152 = 42,467,328
    ushort* w2T_lo = w2T_hi + 42467328;
    // moe2 split-K x4 partials overlay the (then-dead) w1T planes:
    // w1T_hi float offset = 28,389,392 + 10,616,832/2 = 33,697,808;
    // capacity 42,467,328 floats >= 4 * 4,718,592. Uniform stride 4,718,592.
    float* eo4 = ws + 33697808;

    zero_counts<<<1, 64, 0, stream>>>(counts);
    // weight transpose+split
    wsplit<<<dim3(3456 / 32, 1152 / 32, 1), 256, 0, stream>>>(qkv_w, qkvT_hi, qkvT_lo, 1152, 3456);
    wsplit<<<dim3(1152 / 32, 1152 / 32, 1), 256, 0, stream>>>(proj_w, projT_hi, projT_lo, 1152, 1152);
    wsplit<<<dim3(4608 / 32, 1152 / 32, E_), 256, 0, stream>>>(w1, w1T_hi, w1T_lo, 1152, 4608);
    wsplit<<<dim3(1152 / 32, 4608 / 32, E_), 256, 0, stream>>>(w2, w2T_hi, w2T_lo, 4608, 1152);

    adaln_kernel<<<dim3(18, 8), 256, 0, stream>>>(c, adaln_w, adaln_b, mod);
    ln_kernel<<<N_TOK, 256, 0, stream>>>(x, mod, buf1, 1);
    // qkv: 27 nt x 16 mt = 432 blocks, n-fastest swizzle (A-panel reuse)
    mfma_gemm<0, 1, 0><<<dim3(432, 1, 1), 256, 0, stream>>>(
        buf1, qkvT_hi, qkvT_lo, qkv_b, qkvb, N_TOK, 3456, D_, 0ULL,
        nullptr, nullptr, nullptr);
    attn_kernel<<<dim3(8, H_, B_), 256, 0, stream>>>(qkvb, atto);
    // proj: 9 nt x 16 mt = 144 blocks, split-K x4 -> o2[0..3]
    mfma_gemm<0, 4, 0><<<dim3(144, 1, 4), 256, 0, stream>>>(
        atto, projT_hi, projT_lo, proj_b, o2, N_TOK, D_, D_, 2359296ULL,
        nullptr, nullptr, nullptr);
    residual1<<<(N_TOK * D_) / 256, 256, 0, stream>>>(x, o2, mod, xa);
    ln_kernel<<<N_TOK, 256, 0, stream>>>(xa, nullptr, buf1, 0);
    router_kernel<<<N_TOK, 64, 0, stream>>>(buf1, gate_w, gate_b, counts, etok, eslot,
                                            tslot, tscore);
    // moe1: 36 nt x 16 mt = 576 blocks/expert, m-fastest swizzle (B-panel reuse)
    mfma_gemm<1, 1, 1><<<dim3(576, 1, E_), 256, 0, stream>>>(
        buf1, w1T_hi, w1T_lo, b1, h1, N_TOK, MLPH, D_, 0ULL,
        counts, etok, eslot);
    // moe2: 9 nt x 16 mt = 144 blocks/expert, split-K x4 -> eo4[0..3]
    mfma_gemm<2, 4, 0><<<dim3(144, 1, E_ * 4), 256, 0, stream>>>(
        h1, w2T_hi, w2T_lo, b2, eo4, N_TOK, D_, MLPH, 4718592ULL,
        counts, eslot, eslot);
    combine_kernel<<<(N_TOK * D_) / 256, 256, 0, stream>>>(xa, eo4, mod, tslot,
                                                           tscore, (float*)d_out);
}